// Round 10
// baseline (372.469 us; speedup 1.0000x reference)
//
#include <hip/hip_runtime.h>
#include <hip/hip_bf16.h>

#define D_MODEL 256
#define D_HID   128
#define SEQ     1024
#define NBATCH  32
#define NROWS   (NBATCH * SEQ)    // 32768
#define MASKV   -10000.0f
#define EPSLN   1e-5f

typedef unsigned short u16;
using bf16x8 = __attribute__((ext_vector_type(8))) short;
using f32x4  = __attribute__((ext_vector_type(4))) float;

union U8 { uint4 v; u16 s[8]; };

__device__ __forceinline__ float bf2f(u16 u) {
    unsigned int x = ((unsigned int)u) << 16;
    return __uint_as_float(x);
}
__device__ __forceinline__ u16 f2bf(float f) {
    unsigned int u = __float_as_uint(f);
    u += 0x7fff + ((u >> 16) & 1);   // RNE
    return (u16)(u >> 16);
}
__device__ __forceinline__ void load4(const float* p, float* f) {
    float4 a = *(const float4*)p;
    f[0] = a.x; f[1] = a.y; f[2] = a.z; f[3] = a.w;
}
__device__ __forceinline__ void load4(const u16* p, float* f) {
    ushort4 v = *(const ushort4*)p;
    f[0] = bf2f(v.x); f[1] = bf2f(v.y); f[2] = bf2f(v.z); f[3] = bf2f(v.w);
}
// async global->LDS, 16B per lane; LDS dest = wave-uniform base + lane*16
__device__ __forceinline__ void gload16(const u16* g, u16* l) {
    __builtin_amdgcn_global_load_lds(
        (const __attribute__((address_space(1))) void*)g,
        (__attribute__((address_space(3))) void*)l, 16, 0, 0);
}

// DPP cross-lane: VALU-pipe butterfly over 16-lane groups.
template <int CTRL>
__device__ __forceinline__ float dpp_mov(float v) {
    return __int_as_float(__builtin_amdgcn_update_dpp(
        0, __float_as_int(v), CTRL, 0xf, 0xf, true));
}
__device__ __forceinline__ float red16_max(float v) {
    v = fmaxf(v, dpp_mov<0xB1>(v));
    v = fmaxf(v, dpp_mov<0x4E>(v));
    v = fmaxf(v, dpp_mov<0x141>(v));
    v = fmaxf(v, dpp_mov<0x140>(v));
    return v;
}
__device__ __forceinline__ float red16_sum(float v) {
    v += dpp_mov<0xB1>(v);
    v += dpp_mov<0x4E>(v);
    v += dpp_mov<0x141>(v);
    v += dpp_mov<0x140>(v);
    return v;
}

// ---------------------------------------------------------------------------
// Weight transposes: fp32 W[K][N] -> bf16 WT[N][K]
// ---------------------------------------------------------------------------
__global__ __launch_bounds__(256) void transpose_weights(
    const float* __restrict__ wqkv, u16* __restrict__ wqkvT,
    const float* __restrict__ wproj, u16* __restrict__ wprojT,
    const float* __restrict__ wfc1, u16* __restrict__ wfc1T,
    const float* __restrict__ wfc2, u16* __restrict__ wfc2T) {
    int tid = blockIdx.x * 256 + threadIdx.x;
    int stride = gridDim.x * 256;
    for (int i = tid; i < 768 * 256; i += stride) {
        int n = i >> 8, k = i & 255;
        wqkvT[i] = f2bf(wqkv[k * 768 + n]);
    }
    for (int i = tid; i < 256 * 256; i += stride) {
        int n = i >> 8, k = i & 255;
        wprojT[i] = f2bf(wproj[k * 256 + n]);
    }
    for (int i = tid; i < 128 * 256; i += stride) {
        int n = i >> 8, k = i & 255;
        wfc1T[i] = f2bf(wfc1[k * 128 + n]);
    }
    for (int i = tid; i < 256 * 128; i += stride) {
        int n = i >> 7, k = i & 127;
        wfc2T[i] = f2bf(wfc2[k * 256 + n]);
    }
}

// ---------------------------------------------------------------------------
// Fused LayerNorm: one wave per row (256 cols, 4/lane), writes bf16 row.
// ---------------------------------------------------------------------------
template <typename TX>
__global__ __launch_bounds__(256) void ln_fused(
    const TX* __restrict__ x, const float* __restrict__ gamma,
    const float* __restrict__ beta, u16* __restrict__ out) {
    int wave = threadIdx.x >> 6, lane = threadIdx.x & 63;
    int row = blockIdx.x * 4 + wave;
    float f[4];
    load4(x + (size_t)row * D_MODEL + lane * 4, f);
    float s  = f[0] + f[1] + f[2] + f[3];
    float sq = f[0] * f[0] + f[1] * f[1] + f[2] * f[2] + f[3] * f[3];
    #pragma unroll
    for (int off = 1; off < 64; off <<= 1) {
        s  += __shfl_xor(s, off);
        sq += __shfl_xor(sq, off);
    }
    float mu   = s * (1.0f / 256.0f);
    float var  = sq * (1.0f / 256.0f) - mu * mu;
    float rstd = rsqrtf(var + EPSLN);
    float g[4], be[4];
    load4(gamma + lane * 4, g);
    load4(beta + lane * 4, be);
    ushort4 o;
    o.x = f2bf((f[0] - mu) * rstd * g[0] + be[0]);
    o.y = f2bf((f[1] - mu) * rstd * g[1] + be[1]);
    o.z = f2bf((f[2] - mu) * rstd * g[2] + be[2]);
    o.w = f2bf((f[3] - mu) * rstd * g[3] + be[3]);
    *(ushort4*)(out + (size_t)row * D_MODEL + lane * 4) = o;
}

// ---------------------------------------------------------------------------
// 128x128 GEMM tile mainloop (m97-class): single 64-KB LDS buffer, staged via
// global_load_lds width-16 with inverse-XOR-swizzled GLOBAL source (rule #21);
// ds_read_b128 frag reads apply the same XOR -> 2-way (free) bank aliasing.
// 4 waves in 2x2, each owns a 64x64 quadrant (acc[4][4]).
// ---------------------------------------------------------------------------
#define GT2_ELEMS (2 * 128 * 128)   // A tile + B tile, 64 KB

template <int K>
__device__ __forceinline__ void gemm_tile2(
    const u16* __restrict__ A, const u16* __restrict__ BT,
    int m0, int n0, u16* lds, f32x4 acc[4][4]) {
    u16* ldsA = lds;
    u16* ldsB = lds + 128 * 128;
    const int tid = threadIdx.x;
    const int lane = tid & 63, wave = tid >> 6;
    const int wr = (wave >> 1) * 64, wc = (wave & 1) * 64;
    const int row = lane & 15, quad = lane >> 4;

    for (int ks = 0; ks < K; ks += 128) {
        __syncthreads();
        #pragma unroll
        for (int i = 0; i < 8; i++) {
            int blk = i * 4 + wave;               // 1-KB block 0..31
            int B = (blk << 10) + lane * 16;      // byte offset in 32-KB tile
            int r = B >> 8;                       // tile row (256-B rows)
            int cb = (B & 255) ^ ((r & 7) << 4);  // inverse-swizzled byte col
            gload16(A + (size_t)(m0 + r) * K + ks + (cb >> 1),
                    ldsA + (blk << 9));
            gload16(BT + (size_t)(n0 + r) * K + ks + (cb >> 1),
                    ldsB + (blk << 9));
        }
        __syncthreads();
        #pragma unroll
        for (int k0 = 0; k0 < 128; k0 += 32) {
            bf16x8 a[4], b[4];
            #pragma unroll
            for (int mi = 0; mi < 4; mi++) {
                int rr = wr + mi * 16 + row;
                a[mi] = *(const bf16x8*)(ldsA + rr * 128 +
                         ((k0 + quad * 8) ^ ((rr & 7) << 3)));
            }
            #pragma unroll
            for (int nj = 0; nj < 4; nj++) {
                int rr = wc + nj * 16 + row;
                b[nj] = *(const bf16x8*)(ldsB + rr * 128 +
                         ((k0 + quad * 8) ^ ((rr & 7) << 3)));
            }
            #pragma unroll
            for (int mi = 0; mi < 4; mi++)
                #pragma unroll
                for (int nj = 0; nj < 4; nj++)
                    acc[mi][nj] = __builtin_amdgcn_mfma_f32_16x16x32_bf16(
                        a[mi], b[nj], acc[mi][nj], 0, 0, 0);
        }
    }
}

#define ZERO_ACC4(acc)                                       \
    _Pragma("unroll") for (int i_ = 0; i_ < 4; i_++)         \
    _Pragma("unroll") for (int j_ = 0; j_ < 4; j_++)         \
    _Pragma("unroll") for (int e_ = 0; e_ < 4; e_++) acc[i_][j_][e_] = 0.0f;

#define EPILOG_IDX4                                          \
    int lane = threadIdx.x & 63, wave = threadIdx.x >> 6;    \
    int wr = (wave >> 1) * 64, wc = (wave & 1) * 64;         \
    int row = lane & 15, quad = lane >> 4;

// QKV: h @ wqkv + b -> q (pre-scaled 1/16), k, vT[b,256,s]
__global__ __launch_bounds__(256) void gemm_qkv(
    const u16* __restrict__ h, const u16* __restrict__ wqkvT,
    const float* __restrict__ b_qkv,
    u16* __restrict__ q, u16* __restrict__ kk, u16* __restrict__ vT) {
    __shared__ u16 lds[GT2_ELEMS];
    f32x4 acc[4][4];
    ZERO_ACC4(acc)
    int m0 = blockIdx.x * 128, n0 = blockIdx.y * 128;
    gemm_tile2<256>(h, wqkvT, m0, n0, lds, acc);
    EPILOG_IDX4
    #pragma unroll
    for (int mi = 0; mi < 4; mi++) {
        #pragma unroll
        for (int nj = 0; nj < 4; nj++) {
            int gn = n0 + wc + nj * 16 + row;
            float bias = b_qkv[gn];
            int gm = m0 + wr + mi * 16 + quad * 4;
            if (gn < 256) {          // q, pre-scaled by 1/sqrt(D)=1/16
                #pragma unroll
                for (int r = 0; r < 4; r++)
                    q[(size_t)(gm + r) * 256 + gn] =
                        f2bf((acc[mi][nj][r] + bias) * 0.0625f);
            } else if (gn < 512) {   // k
                int col = gn - 256;
                #pragma unroll
                for (int r = 0; r < 4; r++)
                    kk[(size_t)(gm + r) * 256 + col] = f2bf(acc[mi][nj][r] + bias);
            } else {                 // v -> vT[b][d][s]
                int d = gn - 512;
                int b = gm >> 10, s = gm & 1023;
                ushort4 pack;
                pack.x = f2bf(acc[mi][nj][0] + bias);
                pack.y = f2bf(acc[mi][nj][1] + bias);
                pack.z = f2bf(acc[mi][nj][2] + bias);
                pack.w = f2bf(acc[mi][nj][3] + bias);
                *(ushort4*)(vT + ((size_t)(b * 256 + d) << 10) + s) = pack;
            }
        }
    }
}

// proj: ao @ wproj + b + residual(x fp32) -> x2 (bf16)
__global__ __launch_bounds__(256) void gemm_proj(
    const u16* __restrict__ ao, const u16* __restrict__ wprojT,
    const float* __restrict__ b_proj, const float* __restrict__ x_in,
    u16* __restrict__ x2) {
    __shared__ u16 lds[GT2_ELEMS];
    f32x4 acc[4][4];
    ZERO_ACC4(acc)
    int m0 = blockIdx.x * 128, n0 = blockIdx.y * 128;
    gemm_tile2<256>(ao, wprojT, m0, n0, lds, acc);
    EPILOG_IDX4
    #pragma unroll
    for (int mi = 0; mi < 4; mi++)
        #pragma unroll
        for (int nj = 0; nj < 4; nj++) {
            int gn = n0 + wc + nj * 16 + row;
            float bias = b_proj[gn];
            int gm = m0 + wr + mi * 16 + quad * 4;
            #pragma unroll
            for (int r = 0; r < 4; r++) {
                size_t idx = (size_t)(gm + r) * 256 + gn;
                x2[idx] = f2bf(acc[mi][nj][r] + bias + x_in[idx]);
            }
        }
}

// ---------------------------------------------------------------------------
// gemm_mlp: fused LN2 + fc1(ReLU) + fc2 + residual. One block per 128 rows,
// 256 threads, 128 KB LDS, 1 block/CU, grid 256.
//   R0 (64KB): x2 tile (LN'd in place) -> later reused for wfc2T
//   R1 (32KB): wfc1T k-half staging
//   R2 (32KB): a1 = relu(fc1) bf16 128x128
// ---------------------------------------------------------------------------
__global__ __launch_bounds__(256) void gemm_mlp(
    const u16* __restrict__ x2, const float* __restrict__ g2,
    const float* __restrict__ be2,
    const u16* __restrict__ wfc1T, const float* __restrict__ b_fc1,
    const u16* __restrict__ wfc2T, const float* __restrict__ b_fc2,
    float* __restrict__ out) {
    __shared__ u16 lds[65536];            // 128 KB
    u16* ldsB1 = lds + 32768;             // R1
    u16* ldsA1 = lds + 49152;             // R2
    const int tid = threadIdx.x;
    const int lane = tid & 63, wave = tid >> 6;
    const int rowl = lane & 15, quad = lane >> 4;
    const int wr = (wave >> 1) * 64, wc = (wave & 1) * 64;
    const int m0 = blockIdx.x * 128;

    // ---- stage x2 tile (128 x 512B) + wfc1T ks=0 half ----
    #pragma unroll
    for (int i = 0; i < 16; i++) {
        int blk = i * 4 + wave;
        int B = (blk << 10) + lane * 16;
        int r = B >> 9;
        int cb = (B & 511) ^ ((r & 7) << 4);
        gload16(x2 + (size_t)(m0 + r) * 256 + (cb >> 1), lds + (B >> 1));
    }
    #pragma unroll
    for (int i = 0; i < 8; i++) {
        int blk = i * 4 + wave;
        int B = (blk << 10) + lane * 16;
        int r = B >> 8;
        int cb = (B & 255) ^ ((r & 7) << 4);
        gload16(wfc1T + (size_t)r * 256 + 0 + (cb >> 1), ldsB1 + (B >> 1));
    }
    __syncthreads();

    // ---- LN2 in place: wave handles rows wave, wave+4, ... (32 rows) ----
    {
        float4 g4  = *(const float4*)(g2 + lane * 4);
        float4 be4 = *(const float4*)(be2 + lane * 4);
        #pragma unroll 4
        for (int i = 0; i < 32; i++) {
            int r = wave + i * 4;
            char* p = (char*)lds + r * 512 + ((lane * 8) ^ ((r & 7) << 4));
            ushort4 v = *(ushort4*)p;
            float f0 = bf2f(v.x), f1 = bf2f(v.y), f2v = bf2f(v.z), f3 = bf2f(v.w);
            float s  = f0 + f1 + f2v + f3;
            float sq = f0*f0 + f1*f1 + f2v*f2v + f3*f3;
            s = red16_sum(s);   s += __shfl_xor(s, 16);   s += __shfl_xor(s, 32);
            sq = red16_sum(sq); sq += __shfl_xor(sq, 16); sq += __shfl_xor(sq, 32);
            float mu   = s * (1.0f / 256.0f);
            float var  = sq * (1.0f / 256.0f) - mu * mu;
            float rstd = rsqrtf(var + EPSLN);
            ushort4 o;
            o.x = f2bf((f0  - mu) * rstd * g4.x + be4.x);
            o.y = f2bf((f1  - mu) * rstd * g4.y + be4.y);
            o.z = f2bf((f2v - mu) * rstd * g4.z + be4.z);
            o.w = f2bf((f3  - mu) * rstd * g4.w + be4.w);
            *(ushort4*)p = o;
        }
    }
    __syncthreads();

    // ---- fc1: h2tile(128x256) @ wfc1 -> acc1 (128x128) ----
    f32x4 acc1[4][4];
    ZERO_ACC4(acc1)
    #pragma unroll
    for (int ks = 0; ks < 256; ks += 128) {
        if (ks) {
            __syncthreads();          // done reading previous B1 half
            #pragma unroll
            for (int i = 0; i < 8; i++) {
                int blk = i * 4 + wave;
                int B = (blk << 10) + lane * 16;
                int r = B >> 8;
                int cb = (B & 255) ^ ((r & 7) << 4);
                gload16(wfc1T + (size_t)r * 256 + ks + (cb >> 1),
                        ldsB1 + (B >> 1));
            }
            __syncthreads();
        }
        #pragma unroll
        for (int k0 = 0; k0 < 128; k0 += 32) {
            bf16x8 a[4], b[4];
            #pragma unroll
            for (int mi = 0; mi < 4; mi++) {
                int rr = wr + mi * 16 + rowl;
                a[mi] = *(const bf16x8*)((const char*)lds + rr * 512 +
                         ((((ks + k0 + quad * 8) << 1)) ^ ((rr & 7) << 4)));
            }
            #pragma unroll
            for (int nj = 0; nj < 4; nj++) {
                int rb = wc + nj * 16 + rowl;
                b[nj] = *(const bf16x8*)((const char*)ldsB1 + rb * 256 +
                         ((((k0 + quad * 8) << 1)) ^ ((rb & 7) << 4)));
            }
            #pragma unroll
            for (int mi = 0; mi < 4; mi++)
                #pragma unroll
                for (int nj = 0; nj < 4; nj++)
                    acc1[mi][nj] = __builtin_amdgcn_mfma_f32_16x16x32_bf16(
                        a[mi], b[nj], acc1[mi][nj], 0, 0, 0);
        }
    }
    // relu+bias -> a1 (LDS, swizzled scalar writes)
    #pragma unroll
    for (int mi = 0; mi < 4; mi++)
        #pragma unroll
        for (int nj = 0; nj < 4; nj++) {
            int gn_l = wc + nj * 16 + rowl;
            float bias = b_fc1[gn_l];
            #pragma unroll
            for (int r = 0; r < 4; r++) {
                int gm_l = wr + mi * 16 + quad * 4 + r;
                *(u16*)((char*)ldsA1 + gm_l * 256 +
                        (((gn_l << 1)) ^ ((gm_l & 7) << 4))) =
                    f2bf(fmaxf(acc1[mi][nj][r] + bias, 0.0f));
            }
        }
    __syncthreads();                  // a1 visible; x2 tile (R0) now dead

    // ---- stage wfc2T (256 x 256B) into R0 ----
    #pragma unroll
    for (int i = 0; i < 16; i++) {
        int blk = i * 4 + wave;
        int B = (blk << 10) + lane * 16;
        int r = B >> 8;
        int cb = (B & 255) ^ ((r & 7) << 4);
        gload16(wfc2T + (size_t)r * 128 + (cb >> 1), lds + (B >> 1));
    }
    __syncthreads();

    // ---- fc2: a1(128x128) @ wfc2 -> out (128x256) + bias + residual ----
    const int wc2 = (wave & 1) * 128;
    f32x4 acc2[4][8];
    #pragma unroll
    for (int mi = 0; mi < 4; mi++)
        #pragma unroll
        for (int nj = 0; nj < 8; nj++)
            #pragma unroll
            for (int e = 0; e < 4; e++) acc2[mi][nj][e] = 0.0f;
    #pragma unroll
    for (int k0 = 0; k0 < 128; k0 += 32) {
        bf16x8 a[4], b[8];
        #pragma unroll
        for (int mi = 0; mi < 4; mi++) {
            int rr = wr + mi * 16 + rowl;
            a[mi] = *(const bf16x8*)((const char*)ldsA1 + rr * 256 +
                     ((((k0 + quad * 8) << 1)) ^ ((rr & 7) << 4)));
        }
        #pragma unroll
        for (int nj = 0; nj < 8; nj++) {
            int rb = wc2 + nj * 16 + rowl;
            b[nj] = *(const bf16x8*)((const char*)lds + rb * 256 +
                     ((((k0 + quad * 8) << 1)) ^ ((rb & 7) << 4)));
        }
        #pragma unroll
        for (int mi = 0; mi < 4; mi++)
            #pragma unroll
            for (int nj = 0; nj < 8; nj++)
                acc2[mi][nj] = __builtin_amdgcn_mfma_f32_16x16x32_bf16(
                    a[mi], b[nj], acc2[mi][nj], 0, 0, 0);
    }
    #pragma unroll
    for (int mi = 0; mi < 4; mi++)
        #pragma unroll
        for (int nj = 0; nj < 8; nj++) {
            int gn = wc2 + nj * 16 + rowl;
            float bias = b_fc2[gn];
            int gm = m0 + wr + mi * 16 + quad * 4;
            #pragma unroll
            for (int r = 0; r < 4; r++) {
                size_t idx = (size_t)(gm + r) * 256 + gn;
                out[idx] = acc2[mi][nj][r] + bias + bf2f(x2[idx]);
            }
        }
}

// ---------------------------------------------------------------------------
// Flash attention v11: 512-thread blocks (8 waves x 16 rows = 128 q-rows);
// per-wave code identical to the proven 62-us kernel; each staged 32-KB K/V
// tile feeds 8 waves (staging/barriers per compute halved vs round 8).
// RACE FIX vs v10 (G16: no dispatch-order assumptions): split halves may NOT
// write ao (= Q buffer) in place, because the sibling half reads the same Q
// rows at its own start. Now BOTH halves write unnormalized partials;
// attn_merge produces the final rows. qt=0 is left unsplit (4 tiles): its
// single block is the sole reader of Q rows [0,128), so a direct normalized
// ao write is safe.
// Work: 15 chunks/batch (qt0 whole = 4 tiles; qt1..7 split halves of 2qt+2),
// grid 480 over 512 slots; co-resident pairs (c,c+8) sum 18-20, solo = 16.
// Partial layout in d_out (33.55 MB): h0 partials [0,14.68MB) pq<<15 u16,
// h1 partials [14.68,29.36MB), (m,l) 459KB at float offset 7340032.
// ---------------------------------------------------------------------------
__constant__ unsigned char CQT[15] = {7,6,6,5,5,4,4,7, 0,1,1,2,2,3,3};
__constant__ unsigned char CH[15]  = {0,0,1,0,1,0,1,1, 2,0,1,0,1,0,1};

__global__ __launch_bounds__(512, 4) void attn_kernel(
    const u16* __restrict__ q, const u16* __restrict__ k,
    const u16* __restrict__ vT, u16* __restrict__ ao,
    u16* __restrict__ part, float* __restrict__ ml) {
    __shared__ u16 k_lds[2][32 * 256];   // 2 x 16 KB, K tile [s][d]
    __shared__ u16 v_lds[2][256 * 32];   // 2 x 16 KB, V^T tile [d][s]
    __shared__ u16 p_lds[8][16 * 40];    // 10 KB, wave-private P staging

    int j = blockIdx.x;
    int b = j & 31, c = j >> 5;          // batch fast-varying: XCD = b % 8
    int qt = CQT[c], ch = CH[c];
    int span = 2 * qt + 2;
    int lo, hi;
    if (ch == 2) { lo = 0; hi = 4; }            // qt=0 whole (4 tiles)
    else         { lo = ch * span; hi = lo + span; }

    int tid = threadIdx.x;
    int lane = tid & 63, wave = tid >> 6;   // wave 0..7
    int row = lane & 15, quad = lane >> 4;
    int qrow0 = qt * 128 + wave * 16;

    const u16* qb = q + ((size_t)b << 10) * 256;
    const u16* kb = k + ((size_t)b << 10) * 256;
    const u16* vb = vT + (((size_t)b * 256) << 10);

    const int kxor = (row & 7) << 3;   // u16-unit XOR for K reads
    const int vxor = (row & 6) << 2;   // u16-unit XOR for V reads

    // Q fragments held in registers for the whole kernel (pre-scaled by 1/16)
    bf16x8 qf[8];
    #pragma unroll
    for (int kf = 0; kf < 8; kf++)
        qf[kf] = *(const bf16x8*)(qb + (size_t)(qrow0 + row) * 256 + kf * 32 + quad * 8);

    f32x4 o[16];
    #pragma unroll
    for (int n = 0; n < 16; n++)
        #pragma unroll
        for (int e = 0; e < 4; e++) o[n][e] = 0.0f;
    float m_i[4], l_i[4];
    #pragma unroll
    for (int r = 0; r < 4; r++) { m_i[r] = -1e30f; l_i[r] = 0.0f; }

    int wlast = 4 * qt + (wave >> 1);    // this wave's diagonal k-tile

    // stage tile kt: 8 waves x (2 K-blocks + 2 V-blocks) x 1 KB
    auto stage = [&](int bf, int kt) {
        int k0 = kt << 5;
        #pragma unroll
        for (int cc = 0; cc < 2; cc++) {
            int blk = wave * 2 + cc;                  // 0..15
            int B = (blk << 10) + lane * 16;          // byte offset in 16KB tile
            // K: 32 rows x 512 B
            int rk = B >> 9;
            int ck = (B & 511) ^ ((rk & 7) << 4);
            gload16(kb + (size_t)(k0 + rk) * 256 + (ck >> 1),
                    &k_lds[bf][blk << 9]);
            // V^T: 256 rows x 64 B
            int rv = B >> 6;
            int cv = (B & 63) ^ ((rv & 6) << 3);
            gload16(vb + ((size_t)rv << 10) + k0 + (cv >> 1),
                    &v_lds[bf][blk << 9]);
        }
    };

    stage(0, lo);
    __syncthreads();                       // vmcnt(0) drain + barrier

    for (int kt = lo; kt < hi; kt++) {
        int cur = (kt - lo) & 1;
        if (kt + 1 < hi) stage(cur ^ 1, kt + 1);   // prefetch next tile
        if (kt <= wlast) {
            const u16* kl = k_lds[cur];
            const u16* vl = v_lds[cur];

            // S = Q K^T : 16 x 32
            f32x4 sf[2];
            #pragma unroll
            for (int jn = 0; jn < 2; jn++)
                #pragma unroll
                for (int e = 0; e < 4; e++) sf[jn][e] = 0.0f;
            __builtin_amdgcn_s_setprio(1);
            #pragma unroll
            for (int kf = 0; kf < 8; kf++)
                #pragma unroll
                for (int jn = 0; jn < 2; jn++) {
                    bf16x8 bfrag = *(const bf16x8*)(kl +
                        ((((jn * 16 + row) * 256) + kf * 32 + quad * 8) ^ kxor));
                    sf[jn] = __builtin_amdgcn_mfma_f32_16x16x32_bf16(
                        qf[kf], bfrag, sf[jn], 0, 0, 0);
                }
            __builtin_amdgcn_s_setprio(0);

            int kk0 = kt * 32;
            bool diag = (kt == wlast);     // only the diagonal tile masks
            int qrow = qrow0 + quad * 4;
            float sv[2][4];
            #pragma unroll
            for (int jn = 0; jn < 2; jn++)
                #pragma unroll
                for (int r = 0; r < 4; r++) {
                    float v = sf[jn][r];
                    if (diag && (kk0 + jn * 16 + row > qrow + r)) v = MASKV;
                    sv[jn][r] = v;
                }

            // online softmax with defer-max (THR=8); DPP reduces (VALU pipe)
            float pmax[4];
            int need = 0;
            #pragma unroll
            for (int r = 0; r < 4; r++) {
                pmax[r] = red16_max(fmaxf(sv[0][r], sv[1][r]));
                need |= (pmax[r] > m_i[r] + 8.0f) ? 1 : 0;
            }
            if (__any(need)) {
                #pragma unroll
                for (int r = 0; r < 4; r++) {
                    float mnew = fmaxf(m_i[r], pmax[r]);
                    float al = __expf(m_i[r] - mnew);
                    m_i[r] = mnew;
                    l_i[r] *= al;
                    #pragma unroll
                    for (int n = 0; n < 16; n++) o[n][r] *= al;
                }
            }
            #pragma unroll
            for (int r = 0; r < 4; r++) {
                float ps = 0.0f;
                #pragma unroll
                for (int jn = 0; jn < 2; jn++) {
                    sv[jn][r] = __expf(sv[jn][r] - m_i[r]);
                    ps += sv[jn][r];
                }
                l_i[r] += red16_sum(ps);
            }

            // P: C-layout -> wave-private LDS -> A-layout (one frag, K=32)
            u16* pw = p_lds[wave];
            #pragma unroll
            for (int jn = 0; jn < 2; jn++)
                #pragma unroll
                for (int r = 0; r < 4; r++)
                    pw[(quad * 4 + r) * 40 + jn * 16 + row] = f2bf(sv[jn][r]);
            bf16x8 pf = *(const bf16x8*)(pw + row * 40 + quad * 8);

            // O += P V
            __builtin_amdgcn_s_setprio(1);
            #pragma unroll
            for (int n = 0; n < 16; n++) {
                bf16x8 bv = *(const bf16x8*)(vl +
                    ((((n * 16 + row) * 32) + quad * 8) ^ vxor));
                o[n] = __builtin_amdgcn_mfma_f32_16x16x32_bf16(pf, bv, o[n], 0, 0, 0);
            }
            __builtin_amdgcn_s_setprio(0);
        }
        __syncthreads();   // vmcnt(0): prefetched tile landed; buffers swap
    }

    if (ch == 2) {
        // qt=0 whole: sole reader of its Q rows -> safe to write ao directly
        float inv[4];
        #pragma unroll
        for (int r = 0; r < 4; r++) inv[r] = 1.0f / l_i[r];
        u16* aob = ao + (((size_t)b << 10) + qrow0) * 256;
        #pragma unroll
        for (int r = 0; r < 4; r++)
            #pragma unroll
            for (int n = 0; n < 16; n++)
                aob[(size_t)(quad * 4 + r) * 256 + n * 16 + row] =
                    f2bf(o[n][r] * inv[r]);
    } else {
        // split half: write UNNORMALIZED O partial + (m,l); merge finishes.
        int pq = b * 7 + (qt - 1);           // 0..223
        u16* pb = part + ((size_t)(ch * 224 + pq) << 15);
        #pragma unroll
        for (int r = 0; r < 4; r++) {
            int rt = wave * 16 + quad * 4 + r;
            #pragma unroll
            for (int n = 0; n < 16; n++)
                pb[(size_t)rt * 256 + n * 16 + row] = f2bf(o[n][r]);
        }
        if (row == 0) {
            int p = pq * 2 + ch;
            #pragma unroll
            for (int r = 0; r < 4; r++) {
                int rt = wave * 16 + quad * 4 + r;
                float2 v2; v2.x = m_i[r]; v2.y = l_i[r];
                *(float2*)(ml + ((size_t)(p * 128 + rt)) * 2) = v2;
            }
        }
    }
}

// Merge the two k-range halves for qt 1..7. Grid 448 = b*14 + (qt-1)*2 + rh;
// 64 rows per block, 256 threads (row = t>>2, col-quarter = t&3).
__global__ __launch_bounds__(256) void attn_merge(
    const u16* __restrict__ part, const float* __restrict__ ml,
    u16* __restrict__ ao) {
    int j = blockIdx.x;
    int b = j / 14, rem = j - b * 14;
    int qt = (rem >> 1) + 1, rh = rem & 1;
    int t = threadIdx.x;
    int r = t >> 2, cq = t & 3;
    int rt = rh * 64 + r;
    int pq = b * 7 + (qt - 1);
    const float* mlA = ml + ((size_t)((pq * 2 + 0) * 128 + rt)) * 2;
    const float* mlB = ml + ((size_t)((pq * 2 + 1) * 128 + rt)) * 2;
    float mA = mlA[0], lA = mlA[1];
    float mB = mlB[0], lB = mlB[1];
    float m  = fmaxf(mA, mB);
    float eA = __expf(mA - m), eB = __expf(mB - m);
    float inv = 1.0f / (lA * eA + lB * eB);
    float sA = eA * inv, sB = eB * inv;
    const u16* oA = part + ((size_t)pq << 15) + (size_t)rt * 256 + cq * 64;
    const u16* oB = part + ((size_t)(224 + pq) << 15) + (size_t)rt * 256 + cq * 64;
    u16* dst = ao + ((size_t)((b << 10) + qt * 128 + rt)) * 256 + cq * 64;
    #pragma unroll
    for (int u = 0; u < 8; u++) {
        U8 a, bb, o;
        a.v  = *(const uint4*)(oA + u * 8);
        bb.v = *(const uint4*)(oB + u * 8);
        #pragma unroll
        for (int e = 0; e < 8; e++)
            o.s[e] = f2bf(bf2f(a.s[e]) * sA + bf2f(bb.s[e]) * sB);
        *(uint4*)(dst + u * 8) = o.v;
    }
}

// ---------------------------------------------------------------------------
extern "C" void kernel_launch(void* const* d_in, const int* in_sizes, int n_in,
                              void* d_out, int out_size, void* d_ws, size_t ws_size,
                              hipStream_t stream) {
    const float* x      = (const float*)d_in[0];
    const float* ln1_s  = (const float*)d_in[1];
    const float* ln1_b  = (const float*)d_in[2];
    const float* w_qkv  = (const float*)d_in[3];
    const float* b_qkv  = (const float*)d_in[4];
    const float* w_proj = (const float*)d_in[5];
    const float* b_proj = (const float*)d_in[6];
    const float* ln2_s  = (const float*)d_in[7];
    const float* ln2_b  = (const float*)d_in[8];
    const float* w_fc1  = (const float*)d_in[9];
    const float* b_fc1  = (const float*)d_in[10];
    const float* w_fc2  = (const float*)d_in[11];
    const float* b_fc2  = (const float*)d_in[12];
    float* out = (float*)d_out;

    // d_out reuse timeline:
    //   ln1 -> h (first 16.8MB) -> consumed by gemm_qkv
    //   attn partials: h0 [0,14.68MB), h1 [14.68,29.36MB), (m,l) 459KB at
    //   float offset 7340032 (29.36MB) -> consumed by attn_merge
    //   gemm_mlp overwrites all of d_out with the final fp32 output last.
    u16* h = (u16*)d_out;                      // LN1(x), then attn partials

    u16* W = (u16*)d_ws;
    u16* wqkvT  = W;                           // 768*256
    u16* wprojT = wqkvT + 196608;              // 256*256
    u16* wfc1T  = wprojT + 65536;              // 128*256
    u16* wfc2T  = wfc1T + 32768;               // 256*128
    u16* buf1   = wfc2T + 32768;               // q, then attn-out (in place)
    u16* buf2   = buf1 + (size_t)NROWS * 256;  // k, then x2
    u16* buf3   = buf2 + (size_t)NROWS * 256;  // vT (dead after attn)

    u16*   part  = h;                          // attn partials (bf16)
    float* mlbuf = (float*)d_out + 7340032;    // attn partial (m,l)

    transpose_weights<<<dim3(64), dim3(256), 0, stream>>>(
        w_qkv, wqkvT, w_proj, wprojT, w_fc1, wfc1T, w_fc2, wfc2T);
    ln_fused<float><<<dim3(NROWS / 4), dim3(256), 0, stream>>>(
        x, ln1_s, ln1_b, h);
    gemm_qkv<<<dim3(NROWS / 128, 6), dim3(256), 0, stream>>>(
        h, wqkvT, b_qkv, buf1, buf2, buf3);
    attn_kernel<<<dim3(480), dim3(512), 0, stream>>>(
        buf1, buf2, buf3, buf1, part, mlbuf);
    attn_merge<<<dim3(448), dim3(256), 0, stream>>>(
        part, mlbuf, buf1);
    gemm_proj<<<dim3(NROWS / 128, 2), dim3(256), 0, stream>>>(
        buf1, wprojT, b_proj, x, buf2);
    gemm_mlp<<<dim3(NROWS / 128), dim3(256), 0, stream>>>(
        buf2, ln2_s, ln2_b, wfc1T, b_fc1, wfc2T, b_fc2, out);
}

// Round 11
// 244.163 us; speedup vs baseline: 1.5255x; 1.5255x over previous
//
#include <hip/hip_runtime.h>
#include <hip/hip_bf16.h>

#define D_MODEL 256
#define D_HID   128
#define SEQ     1024
#define NBATCH  32
#define NROWS   (NBATCH * SEQ)    // 32768
#define MASKV   -10000.0f
#define EPSLN   1e-5f

typedef unsigned short u16;
using bf16x8 = __attribute__((ext_vector_type(8))) short;
using f32x4  = __attribute__((ext_vector_type(4))) float;

union U8 { uint4 v; u16 s[8]; };

__device__ __forceinline__ float bf2f(u16 u) {
    unsigned int x = ((unsigned int)u) << 16;
    return __uint_as_float(x);
}
__device__ __forceinline__ u16 f2bf(float f) {
    unsigned int u = __float_as_uint(f);
    u += 0x7fff + ((u >> 16) & 1);   // RNE
    return (u16)(u >> 16);
}
__device__ __forceinline__ void load4(const float* p, float* f) {
    float4 a = *(const float4*)p;
    f[0] = a.x; f[1] = a.y; f[2] = a.z; f[3] = a.w;
}
__device__ __forceinline__ void load4(const u16* p, float* f) {
    ushort4 v = *(const ushort4*)p;
    f[0] = bf2f(v.x); f[1] = bf2f(v.y); f[2] = bf2f(v.z); f[3] = bf2f(v.w);
}
// async global->LDS, 16B per lane; LDS dest = wave-uniform base + lane*16
__device__ __forceinline__ void gload16(const u16* g, u16* l) {
    __builtin_amdgcn_global_load_lds(
        (const __attribute__((address_space(1))) void*)g,
        (__attribute__((address_space(3))) void*)l, 16, 0, 0);
}

// DPP cross-lane: VALU-pipe butterfly over 16-lane groups.
template <int CTRL>
__device__ __forceinline__ float dpp_mov(float v) {
    return __int_as_float(__builtin_amdgcn_update_dpp(
        0, __float_as_int(v), CTRL, 0xf, 0xf, true));
}
__device__ __forceinline__ float red16_max(float v) {
    v = fmaxf(v, dpp_mov<0xB1>(v));
    v = fmaxf(v, dpp_mov<0x4E>(v));
    v = fmaxf(v, dpp_mov<0x141>(v));
    v = fmaxf(v, dpp_mov<0x140>(v));
    return v;
}
__device__ __forceinline__ float red16_sum(float v) {
    v += dpp_mov<0xB1>(v);
    v += dpp_mov<0x4E>(v);
    v += dpp_mov<0x141>(v);
    v += dpp_mov<0x140>(v);
    return v;
}

// ---------------------------------------------------------------------------
// Weight transposes: fp32 W[K][N] -> bf16 WT[N][K]
// ---------------------------------------------------------------------------
__global__ __launch_bounds__(256) void transpose_weights(
    const float* __restrict__ wqkv, u16* __restrict__ wqkvT,
    const float* __restrict__ wproj, u16* __restrict__ wprojT,
    const float* __restrict__ wfc1, u16* __restrict__ wfc1T,
    const float* __restrict__ wfc2, u16* __restrict__ wfc2T) {
    int tid = blockIdx.x * 256 + threadIdx.x;
    int stride = gridDim.x * 256;
    for (int i = tid; i < 768 * 256; i += stride) {
        int n = i >> 8, k = i & 255;
        wqkvT[i] = f2bf(wqkv[k * 768 + n]);
    }
    for (int i = tid; i < 256 * 256; i += stride) {
        int n = i >> 8, k = i & 255;
        wprojT[i] = f2bf(wproj[k * 256 + n]);
    }
    for (int i = tid; i < 128 * 256; i += stride) {
        int n = i >> 8, k = i & 255;
        wfc1T[i] = f2bf(wfc1[k * 128 + n]);
    }
    for (int i = tid; i < 256 * 128; i += stride) {
        int n = i >> 7, k = i & 127;
        wfc2T[i] = f2bf(wfc2[k * 256 + n]);
    }
}

// ---------------------------------------------------------------------------
// Fused LayerNorm: one wave per row (256 cols, 4/lane), writes bf16 row.
// ---------------------------------------------------------------------------
template <typename TX>
__global__ __launch_bounds__(256) void ln_fused(
    const TX* __restrict__ x, const float* __restrict__ gamma,
    const float* __restrict__ beta, u16* __restrict__ out) {
    int wave = threadIdx.x >> 6, lane = threadIdx.x & 63;
    int row = blockIdx.x * 4 + wave;
    float f[4];
    load4(x + (size_t)row * D_MODEL + lane * 4, f);
    float s  = f[0] + f[1] + f[2] + f[3];
    float sq = f[0] * f[0] + f[1] * f[1] + f[2] * f[2] + f[3] * f[3];
    #pragma unroll
    for (int off = 1; off < 64; off <<= 1) {
        s  += __shfl_xor(s, off);
        sq += __shfl_xor(sq, off);
    }
    float mu   = s * (1.0f / 256.0f);
    float var  = sq * (1.0f / 256.0f) - mu * mu;
    float rstd = rsqrtf(var + EPSLN);
    float g[4], be[4];
    load4(gamma + lane * 4, g);
    load4(beta + lane * 4, be);
    ushort4 o;
    o.x = f2bf((f[0] - mu) * rstd * g[0] + be[0]);
    o.y = f2bf((f[1] - mu) * rstd * g[1] + be[1]);
    o.z = f2bf((f[2] - mu) * rstd * g[2] + be[2]);
    o.w = f2bf((f[3] - mu) * rstd * g[3] + be[3]);
    *(ushort4*)(out + (size_t)row * D_MODEL + lane * 4) = o;
}

// ---------------------------------------------------------------------------
// 128x128 GEMM tile mainloop (m97-class): single 64-KB LDS buffer, staged via
// global_load_lds width-16 with inverse-XOR-swizzled GLOBAL source (rule #21);
// ds_read_b128 frag reads apply the same XOR -> 2-way (free) bank aliasing.
// 4 waves in 2x2, each owns a 64x64 quadrant (acc[4][4]).
// ---------------------------------------------------------------------------
#define GT2_ELEMS (2 * 128 * 128)   // A tile + B tile, 64 KB

template <int K>
__device__ __forceinline__ void gemm_tile2(
    const u16* __restrict__ A, const u16* __restrict__ BT,
    int m0, int n0, u16* lds, f32x4 acc[4][4]) {
    u16* ldsA = lds;
    u16* ldsB = lds + 128 * 128;
    const int tid = threadIdx.x;
    const int lane = tid & 63, wave = tid >> 6;
    const int wr = (wave >> 1) * 64, wc = (wave & 1) * 64;
    const int row = lane & 15, quad = lane >> 4;

    for (int ks = 0; ks < K; ks += 128) {
        __syncthreads();
        #pragma unroll
        for (int i = 0; i < 8; i++) {
            int blk = i * 4 + wave;               // 1-KB block 0..31
            int B = (blk << 10) + lane * 16;      // byte offset in 32-KB tile
            int r = B >> 8;                       // tile row (256-B rows)
            int cb = (B & 255) ^ ((r & 7) << 4);  // inverse-swizzled byte col
            gload16(A + (size_t)(m0 + r) * K + ks + (cb >> 1),
                    ldsA + (blk << 9));
            gload16(BT + (size_t)(n0 + r) * K + ks + (cb >> 1),
                    ldsB + (blk << 9));
        }
        __syncthreads();
        #pragma unroll
        for (int k0 = 0; k0 < 128; k0 += 32) {
            bf16x8 a[4], b[4];
            #pragma unroll
            for (int mi = 0; mi < 4; mi++) {
                int rr = wr + mi * 16 + row;
                a[mi] = *(const bf16x8*)(ldsA + rr * 128 +
                         ((k0 + quad * 8) ^ ((rr & 7) << 3)));
            }
            #pragma unroll
            for (int nj = 0; nj < 4; nj++) {
                int rr = wc + nj * 16 + row;
                b[nj] = *(const bf16x8*)(ldsB + rr * 128 +
                         ((k0 + quad * 8) ^ ((rr & 7) << 3)));
            }
            #pragma unroll
            for (int mi = 0; mi < 4; mi++)
                #pragma unroll
                for (int nj = 0; nj < 4; nj++)
                    acc[mi][nj] = __builtin_amdgcn_mfma_f32_16x16x32_bf16(
                        a[mi], b[nj], acc[mi][nj], 0, 0, 0);
        }
    }
}

#define ZERO_ACC4(acc)                                       \
    _Pragma("unroll") for (int i_ = 0; i_ < 4; i_++)         \
    _Pragma("unroll") for (int j_ = 0; j_ < 4; j_++)         \
    _Pragma("unroll") for (int e_ = 0; e_ < 4; e_++) acc[i_][j_][e_] = 0.0f;

#define EPILOG_IDX4                                          \
    int lane = threadIdx.x & 63, wave = threadIdx.x >> 6;    \
    int wr = (wave >> 1) * 64, wc = (wave & 1) * 64;         \
    int row = lane & 15, quad = lane >> 4;

// QKV: h @ wqkv + b -> q (pre-scaled 1/16), k, vT[b,256,s]
__global__ __launch_bounds__(256) void gemm_qkv(
    const u16* __restrict__ h, const u16* __restrict__ wqkvT,
    const float* __restrict__ b_qkv,
    u16* __restrict__ q, u16* __restrict__ kk, u16* __restrict__ vT) {
    __shared__ u16 lds[GT2_ELEMS];
    f32x4 acc[4][4];
    ZERO_ACC4(acc)
    int m0 = blockIdx.x * 128, n0 = blockIdx.y * 128;
    gemm_tile2<256>(h, wqkvT, m0, n0, lds, acc);
    EPILOG_IDX4
    #pragma unroll
    for (int mi = 0; mi < 4; mi++) {
        #pragma unroll
        for (int nj = 0; nj < 4; nj++) {
            int gn = n0 + wc + nj * 16 + row;
            float bias = b_qkv[gn];
            int gm = m0 + wr + mi * 16 + quad * 4;
            if (gn < 256) {          // q, pre-scaled by 1/sqrt(D)=1/16
                #pragma unroll
                for (int r = 0; r < 4; r++)
                    q[(size_t)(gm + r) * 256 + gn] =
                        f2bf((acc[mi][nj][r] + bias) * 0.0625f);
            } else if (gn < 512) {   // k
                int col = gn - 256;
                #pragma unroll
                for (int r = 0; r < 4; r++)
                    kk[(size_t)(gm + r) * 256 + col] = f2bf(acc[mi][nj][r] + bias);
            } else {                 // v -> vT[b][d][s]
                int d = gn - 512;
                int b = gm >> 10, s = gm & 1023;
                ushort4 pack;
                pack.x = f2bf(acc[mi][nj][0] + bias);
                pack.y = f2bf(acc[mi][nj][1] + bias);
                pack.z = f2bf(acc[mi][nj][2] + bias);
                pack.w = f2bf(acc[mi][nj][3] + bias);
                *(ushort4*)(vT + ((size_t)(b * 256 + d) << 10) + s) = pack;
            }
        }
    }
}

// proj: ao @ wproj + b + residual(x fp32) -> x2 (bf16)
__global__ __launch_bounds__(256) void gemm_proj(
    const u16* __restrict__ ao, const u16* __restrict__ wprojT,
    const float* __restrict__ b_proj, const float* __restrict__ x_in,
    u16* __restrict__ x2) {
    __shared__ u16 lds[GT2_ELEMS];
    f32x4 acc[4][4];
    ZERO_ACC4(acc)
    int m0 = blockIdx.x * 128, n0 = blockIdx.y * 128;
    gemm_tile2<256>(ao, wprojT, m0, n0, lds, acc);
    EPILOG_IDX4
    #pragma unroll
    for (int mi = 0; mi < 4; mi++)
        #pragma unroll
        for (int nj = 0; nj < 4; nj++) {
            int gn = n0 + wc + nj * 16 + row;
            float bias = b_proj[gn];
            int gm = m0 + wr + mi * 16 + quad * 4;
            #pragma unroll
            for (int r = 0; r < 4; r++) {
                size_t idx = (size_t)(gm + r) * 256 + gn;
                x2[idx] = f2bf(acc[mi][nj][r] + bias + x_in[idx]);
            }
        }
}

// ---------------------------------------------------------------------------
// gemm_mlp: fused LN2 + fc1(ReLU) + fc2 + residual. One block per 128 rows,
// 256 threads, 128 KB LDS, 1 block/CU, grid 256.
//   R0 (64KB): x2 tile (LN'd in place) -> later reused for wfc2T
//   R1 (32KB): wfc1T k-half staging
//   R2 (32KB): a1 = relu(fc1) bf16 128x128
// ---------------------------------------------------------------------------
__global__ __launch_bounds__(256) void gemm_mlp(
    const u16* __restrict__ x2, const float* __restrict__ g2,
    const float* __restrict__ be2,
    const u16* __restrict__ wfc1T, const float* __restrict__ b_fc1,
    const u16* __restrict__ wfc2T, const float* __restrict__ b_fc2,
    float* __restrict__ out) {
    __shared__ u16 lds[65536];            // 128 KB
    u16* ldsB1 = lds + 32768;             // R1
    u16* ldsA1 = lds + 49152;             // R2
    const int tid = threadIdx.x;
    const int lane = tid & 63, wave = tid >> 6;
    const int rowl = lane & 15, quad = lane >> 4;
    const int wr = (wave >> 1) * 64, wc = (wave & 1) * 64;
    const int m0 = blockIdx.x * 128;

    // ---- stage x2 tile (128 x 512B) + wfc1T ks=0 half ----
    #pragma unroll
    for (int i = 0; i < 16; i++) {
        int blk = i * 4 + wave;
        int B = (blk << 10) + lane * 16;
        int r = B >> 9;
        int cb = (B & 511) ^ ((r & 7) << 4);
        gload16(x2 + (size_t)(m0 + r) * 256 + (cb >> 1), lds + (B >> 1));
    }
    #pragma unroll
    for (int i = 0; i < 8; i++) {
        int blk = i * 4 + wave;
        int B = (blk << 10) + lane * 16;
        int r = B >> 8;
        int cb = (B & 255) ^ ((r & 7) << 4);
        gload16(wfc1T + (size_t)r * 256 + 0 + (cb >> 1), ldsB1 + (B >> 1));
    }
    __syncthreads();

    // ---- LN2 in place: wave handles rows wave, wave+4, ... (32 rows) ----
    {
        float4 g4  = *(const float4*)(g2 + lane * 4);
        float4 be4 = *(const float4*)(be2 + lane * 4);
        #pragma unroll 4
        for (int i = 0; i < 32; i++) {
            int r = wave + i * 4;
            char* p = (char*)lds + r * 512 + ((lane * 8) ^ ((r & 7) << 4));
            ushort4 v = *(ushort4*)p;
            float f0 = bf2f(v.x), f1 = bf2f(v.y), f2v = bf2f(v.z), f3 = bf2f(v.w);
            float s  = f0 + f1 + f2v + f3;
            float sq = f0*f0 + f1*f1 + f2v*f2v + f3*f3;
            s = red16_sum(s);   s += __shfl_xor(s, 16);   s += __shfl_xor(s, 32);
            sq = red16_sum(sq); sq += __shfl_xor(sq, 16); sq += __shfl_xor(sq, 32);
            float mu   = s * (1.0f / 256.0f);
            float var  = sq * (1.0f / 256.0f) - mu * mu;
            float rstd = rsqrtf(var + EPSLN);
            ushort4 o;
            o.x = f2bf((f0  - mu) * rstd * g4.x + be4.x);
            o.y = f2bf((f1  - mu) * rstd * g4.y + be4.y);
            o.z = f2bf((f2v - mu) * rstd * g4.z + be4.z);
            o.w = f2bf((f3  - mu) * rstd * g4.w + be4.w);
            *(ushort4*)p = o;
        }
    }
    __syncthreads();

    // ---- fc1: h2tile(128x256) @ wfc1 -> acc1 (128x128) ----
    f32x4 acc1[4][4];
    ZERO_ACC4(acc1)
    #pragma unroll
    for (int ks = 0; ks < 256; ks += 128) {
        if (ks) {
            __syncthreads();          // done reading previous B1 half
            #pragma unroll
            for (int i = 0; i < 8; i++) {
                int blk = i * 4 + wave;
                int B = (blk << 10) + lane * 16;
                int r = B >> 8;
                int cb = (B & 255) ^ ((r & 7) << 4);
                gload16(wfc1T + (size_t)r * 256 + ks + (cb >> 1),
                        ldsB1 + (B >> 1));
            }
            __syncthreads();
        }
        #pragma unroll
        for (int k0 = 0; k0 < 128; k0 += 32) {
            bf16x8 a[4], b[4];
            #pragma unroll
            for (int mi = 0; mi < 4; mi++) {
                int rr = wr + mi * 16 + rowl;
                a[mi] = *(const bf16x8*)((const char*)lds + rr * 512 +
                         ((((ks + k0 + quad * 8) << 1)) ^ ((rr & 7) << 4)));
            }
            #pragma unroll
            for (int nj = 0; nj < 4; nj++) {
                int rb = wc + nj * 16 + rowl;
                b[nj] = *(const bf16x8*)((const char*)ldsB1 + rb * 256 +
                         ((((k0 + quad * 8) << 1)) ^ ((rb & 7) << 4)));
            }
            #pragma unroll
            for (int mi = 0; mi < 4; mi++)
                #pragma unroll
                for (int nj = 0; nj < 4; nj++)
                    acc1[mi][nj] = __builtin_amdgcn_mfma_f32_16x16x32_bf16(
                        a[mi], b[nj], acc1[mi][nj], 0, 0, 0);
        }
    }
    // relu+bias -> a1 (LDS, swizzled scalar writes)
    #pragma unroll
    for (int mi = 0; mi < 4; mi++)
        #pragma unroll
        for (int nj = 0; nj < 4; nj++) {
            int gn_l = wc + nj * 16 + rowl;
            float bias = b_fc1[gn_l];
            #pragma unroll
            for (int r = 0; r < 4; r++) {
                int gm_l = wr + mi * 16 + quad * 4 + r;
                *(u16*)((char*)ldsA1 + gm_l * 256 +
                        (((gn_l << 1)) ^ ((gm_l & 7) << 4))) =
                    f2bf(fmaxf(acc1[mi][nj][r] + bias, 0.0f));
            }
        }
    __syncthreads();                  // a1 visible; x2 tile (R0) now dead

    // ---- stage wfc2T (256 x 256B) into R0 ----
    #pragma unroll
    for (int i = 0; i < 16; i++) {
        int blk = i * 4 + wave;
        int B = (blk << 10) + lane * 16;
        int r = B >> 8;
        int cb = (B & 255) ^ ((r & 7) << 4);
        gload16(wfc2T + (size_t)r * 128 + (cb >> 1), lds + (B >> 1));
    }
    __syncthreads();

    // ---- fc2: a1(128x128) @ wfc2 -> out (128x256) + bias + residual ----
    const int wc2 = (wave & 1) * 128;
    f32x4 acc2[4][8];
    #pragma unroll
    for (int mi = 0; mi < 4; mi++)
        #pragma unroll
        for (int nj = 0; nj < 8; nj++)
            #pragma unroll
            for (int e = 0; e < 4; e++) acc2[mi][nj][e] = 0.0f;
    #pragma unroll
    for (int k0 = 0; k0 < 128; k0 += 32) {
        bf16x8 a[4], b[8];
        #pragma unroll
        for (int mi = 0; mi < 4; mi++) {
            int rr = wr + mi * 16 + rowl;
            a[mi] = *(const bf16x8*)((const char*)ldsA1 + rr * 256 +
                     ((((k0 + quad * 8) << 1)) ^ ((rr & 7) << 4)));
        }
        #pragma unroll
        for (int nj = 0; nj < 8; nj++) {
            int rb = wc2 + nj * 16 + rowl;
            b[nj] = *(const bf16x8*)((const char*)lds + rb * 256 +
                     ((((k0 + quad * 8) << 1)) ^ ((rb & 7) << 4)));
        }
        #pragma unroll
        for (int mi = 0; mi < 4; mi++)
            #pragma unroll
            for (int nj = 0; nj < 8; nj++)
                acc2[mi][nj] = __builtin_amdgcn_mfma_f32_16x16x32_bf16(
                    a[mi], b[nj], acc2[mi][nj], 0, 0, 0);
    }
    #pragma unroll
    for (int mi = 0; mi < 4; mi++)
        #pragma unroll
        for (int nj = 0; nj < 8; nj++) {
            int gn = wc2 + nj * 16 + rowl;
            float bias = b_fc2[gn];
            int gm = m0 + wr + mi * 16 + quad * 4;
            #pragma unroll
            for (int r = 0; r < 4; r++) {
                size_t idx = (size_t)(gm + r) * 256 + gn;
                out[idx] = acc2[mi][nj][r] + bias + bf2f(x2[idx]);
            }
        }
}

// ---------------------------------------------------------------------------
// Flash attention v12 = v11 with the launch-bounds spill fixed:
// __launch_bounds__(512) plain (NO second arg). Round-10's (512,4) forced
// VGPR 128->64 -> full spill -> 290MB scratch traffic -> 186us. The body
// naturally allocates ~128 VGPR (rounds 2-8); at 128 VGPR + 75776B LDS the
// residency is 2 blocks x 8 waves = 16 waves/CU, double round 8's.
// Structure: 512-thread blocks (8 waves x 16 rows = 128 q-rows); per-wave
// code identical to the proven 62-us kernel; each staged 32-KB K/V tile
// feeds 8 waves. Both split halves write unnormalized partials (no in-place
// ao writes -> no dispatch-order race); qt=0 whole (sole Q reader) writes ao
// directly. 15 chunks/batch, grid 480; pairs (c,c+8) sum 18-20.
// ---------------------------------------------------------------------------
__constant__ unsigned char CQT[15] = {7,6,6,5,5,4,4,7, 0,1,1,2,2,3,3};
__constant__ unsigned char CH[15]  = {0,0,1,0,1,0,1,1, 2,0,1,0,1,0,1};

__global__ __launch_bounds__(512) void attn_kernel(
    const u16* __restrict__ q, const u16* __restrict__ k,
    const u16* __restrict__ vT, u16* __restrict__ ao,
    u16* __restrict__ part, float* __restrict__ ml) {
    __shared__ u16 k_lds[2][32 * 256];   // 2 x 16 KB, K tile [s][d]
    __shared__ u16 v_lds[2][256 * 32];   // 2 x 16 KB, V^T tile [d][s]
    __shared__ u16 p_lds[8][16 * 40];    // 10 KB, wave-private P staging

    int j = blockIdx.x;
    int b = j & 31, c = j >> 5;          // batch fast-varying: XCD = b % 8
    int qt = CQT[c], ch = CH[c];
    int span = 2 * qt + 2;
    int lo, hi;
    if (ch == 2) { lo = 0; hi = 4; }            // qt=0 whole (4 tiles)
    else         { lo = ch * span; hi = lo + span; }

    int tid = threadIdx.x;
    int lane = tid & 63, wave = tid >> 6;   // wave 0..7
    int row = lane & 15, quad = lane >> 4;
    int qrow0 = qt * 128 + wave * 16;

    const u16* qb = q + ((size_t)b << 10) * 256;
    const u16* kb = k + ((size_t)b << 10) * 256;
    const u16* vb = vT + (((size_t)b * 256) << 10);

    const int kxor = (row & 7) << 3;   // u16-unit XOR for K reads
    const int vxor = (row & 6) << 2;   // u16-unit XOR for V reads

    // Q fragments held in registers for the whole kernel (pre-scaled by 1/16)
    bf16x8 qf[8];
    #pragma unroll
    for (int kf = 0; kf < 8; kf++)
        qf[kf] = *(const bf16x8*)(qb + (size_t)(qrow0 + row) * 256 + kf * 32 + quad * 8);

    f32x4 o[16];
    #pragma unroll
    for (int n = 0; n < 16; n++)
        #pragma unroll
        for (int e = 0; e < 4; e++) o[n][e] = 0.0f;
    float m_i[4], l_i[4];
    #pragma unroll
    for (int r = 0; r < 4; r++) { m_i[r] = -1e30f; l_i[r] = 0.0f; }

    int wlast = 4 * qt + (wave >> 1);    // this wave's diagonal k-tile

    // stage tile kt: 8 waves x (2 K-blocks + 2 V-blocks) x 1 KB
    auto stage = [&](int bf, int kt) {
        int k0 = kt << 5;
        #pragma unroll
        for (int cc = 0; cc < 2; cc++) {
            int blk = wave * 2 + cc;                  // 0..15
            int B = (blk << 10) + lane * 16;          // byte offset in 16KB tile
            // K: 32 rows x 512 B
            int rk = B >> 9;
            int ck = (B & 511) ^ ((rk & 7) << 4);
            gload16(kb + (size_t)(k0 + rk) * 256 + (ck >> 1),
                    &k_lds[bf][blk << 9]);
            // V^T: 256 rows x 64 B
            int rv = B >> 6;
            int cv = (B & 63) ^ ((rv & 6) << 3);
            gload16(vb + ((size_t)rv << 10) + k0 + (cv >> 1),
                    &v_lds[bf][blk << 9]);
        }
    };

    stage(0, lo);
    __syncthreads();                       // vmcnt(0) drain + barrier

    for (int kt = lo; kt < hi; kt++) {
        int cur = (kt - lo) & 1;
        if (kt + 1 < hi) stage(cur ^ 1, kt + 1);   // prefetch next tile
        if (kt <= wlast) {
            const u16* kl = k_lds[cur];
            const u16* vl = v_lds[cur];

            // S = Q K^T : 16 x 32
            f32x4 sf[2];
            #pragma unroll
            for (int jn = 0; jn < 2; jn++)
                #pragma unroll
                for (int e = 0; e < 4; e++) sf[jn][e] = 0.0f;
            __builtin_amdgcn_s_setprio(1);
            #pragma unroll
            for (int kf = 0; kf < 8; kf++)
                #pragma unroll
                for (int jn = 0; jn < 2; jn++) {
                    bf16x8 bfrag = *(const bf16x8*)(kl +
                        ((((jn * 16 + row) * 256) + kf * 32 + quad * 8) ^ kxor));
                    sf[jn] = __builtin_amdgcn_mfma_f32_16x16x32_bf16(
                        qf[kf], bfrag, sf[jn], 0, 0, 0);
                }
            __builtin_amdgcn_s_setprio(0);

            int kk0 = kt * 32;
            bool diag = (kt == wlast);     // only the diagonal tile masks
            int qrow = qrow0 + quad * 4;
            float sv[2][4];
            #pragma unroll
            for (int jn = 0; jn < 2; jn++)
                #pragma unroll
                for (int r = 0; r < 4; r++) {
                    float v = sf[jn][r];
                    if (diag && (kk0 + jn * 16 + row > qrow + r)) v = MASKV;
                    sv[jn][r] = v;
                }

            // online softmax with defer-max (THR=8); DPP reduces (VALU pipe)
            float pmax[4];
            int need = 0;
            #pragma unroll
            for (int r = 0; r < 4; r++) {
                pmax[r] = red16_max(fmaxf(sv[0][r], sv[1][r]));
                need |= (pmax[r] > m_i[r] + 8.0f) ? 1 : 0;
            }
            if (__any(need)) {
                #pragma unroll
                for (int r = 0; r < 4; r++) {
                    float mnew = fmaxf(m_i[r], pmax[r]);
                    float al = __expf(m_i[r] - mnew);
                    m_i[r] = mnew;
                    l_i[r] *= al;
                    #pragma unroll
                    for (int n = 0; n < 16; n++) o[n][r] *= al;
                }
            }
            #pragma unroll
            for (int r = 0; r < 4; r++) {
                float ps = 0.0f;
                #pragma unroll
                for (int jn = 0; jn < 2; jn++) {
                    sv[jn][r] = __expf(sv[jn][r] - m_i[r]);
                    ps += sv[jn][r];
                }
                l_i[r] += red16_sum(ps);
            }

            // P: C-layout -> wave-private LDS -> A-layout (one frag, K=32)
            u16* pw = p_lds[wave];
            #pragma unroll
            for (int jn = 0; jn < 2; jn++)
                #pragma unroll
                for (int r = 0; r < 4; r++)
                    pw[(quad * 4 + r) * 40 + jn * 16 + row] = f2bf(sv[jn][r]);
            bf16x8 pf = *(const bf16x8*)(pw + row * 40 + quad * 8);

            // O += P V
            __builtin_amdgcn_s_setprio(1);
            #pragma unroll
            for (int n = 0; n < 16; n++) {
                bf16x8 bv = *(const bf16x8*)(vl +
                    ((((n * 16 + row) * 32) + quad * 8) ^ vxor));
                o[n] = __builtin_amdgcn_mfma_f32_16x16x32_bf16(pf, bv, o[n], 0, 0, 0);
            }
            __builtin_amdgcn_s_setprio(0);
        }
        __syncthreads();   // vmcnt(0): prefetched tile landed; buffers swap
    }

    if (ch == 2) {
        // qt=0 whole: sole reader of its Q rows -> safe to write ao directly
        float inv[4];
        #pragma unroll
        for (int r = 0; r < 4; r++) inv[r] = 1.0f / l_i[r];
        u16* aob = ao + (((size_t)b << 10) + qrow0) * 256;
        #pragma unroll
        for (int r = 0; r < 4; r++)
            #pragma unroll
            for (int n = 0; n < 16; n++)
                aob[(size_t)(quad * 4 + r) * 256 + n * 16 + row] =
                    f2bf(o[n][r] * inv[r]);
    } else {
        // split half: write UNNORMALIZED O partial + (m,l); merge finishes.
        int pq = b * 7 + (qt - 1);           // 0..223
        u16* pb = part + ((size_t)(ch * 224 + pq) << 15);
        #pragma unroll
        for (int r = 0; r < 4; r++) {
            int rt = wave * 16 + quad * 4 + r;
            #pragma unroll
            for (int n = 0; n < 16; n++)
                pb[(size_t)rt * 256 + n * 16 + row] = f2bf(o[n][r]);
        }
        if (row == 0) {
            int p = pq * 2 + ch;
            #pragma unroll
            for (int r = 0; r < 4; r++) {
                int rt = wave * 16 + quad * 4 + r;
                float2 v2; v2.x = m_i[r]; v2.y = l_i[r];
                *(float2*)(ml + ((size_t)(p * 128 + rt)) * 2) = v2;
            }
        }
    }
}

// Merge the two k-range halves for qt 1..7. Grid 448 = b*14 + (qt-1)*2 + rh;
// 64 rows per block, 256 threads (row = t>>2, col-quarter = t&3).
__global__ __launch_bounds__(256) void attn_merge(
    const u16* __restrict__ part, const float* __restrict__ ml,
    u16* __restrict__ ao) {
    int j = blockIdx.x;
    int b = j / 14, rem = j - b * 14;
    int qt = (rem >> 1) + 1, rh = rem & 1;
    int t = threadIdx.x;
    int r = t >> 2, cq = t & 3;
    int rt = rh * 64 + r;
    int pq = b * 7 + (qt - 1);
    const float* mlA = ml + ((size_t)((pq * 2 + 0) * 128 + rt)) * 2;
    const float* mlB = ml + ((size_t)((pq * 2 + 1) * 128 + rt)) * 2;
    float mA = mlA[0], lA = mlA[1];
    float mB = mlB[0], lB = mlB[1];
    float m  = fmaxf(mA, mB);
    float eA = __expf(mA - m), eB = __expf(mB - m);
    float inv = 1.0f / (lA * eA + lB * eB);
    float sA = eA * inv, sB = eB * inv;
    const u16* oA = part + ((size_t)pq << 15) + (size_t)rt * 256 + cq * 64;
    const u16* oB = part + ((size_t)(224 + pq) << 15) + (size_t)rt * 256 + cq * 64;
    u16* dst = ao + ((size_t)((b << 10) + qt * 128 + rt)) * 256 + cq * 64;
    #pragma unroll
    for (int u = 0; u < 8; u++) {
        U8 a, bb, o;
        a.v  = *(const uint4*)(oA + u * 8);
        bb.v = *(const uint4*)(oB + u * 8);
        #pragma unroll
        for (int e = 0; e < 8; e++)
            o.s[e] = f2bf(bf2f(a.s[e]) * sA + bf2f(bb.s[e]) * sB);
        *(uint4*)(dst + u * 8) = o.v;
    }
}

// ---------------------------------------------------------------------------
extern "C" void kernel_launch(void* const* d_in, const int* in_sizes, int n_in,
                              void* d_out, int out_size, void* d_ws, size_t ws_size,
                              hipStream_t stream) {
    const float* x      = (const float*)d_in[0];
    const float* ln1_s  = (const float*)d_in[1];
    const float* ln1_b  = (const float*)d_in[2];
    const float* w_qkv  = (const float*)d_in[3];
    const float* b_qkv  = (const float*)d_in[4];
    const float* w_proj = (const float*)d_in[5];
    const float* b_proj = (const float*)d_in[6];
    const float* ln2_s  = (const float*)d_in[7];
    const float* ln2_b  = (const float*)d_in[8];
    const float* w_fc1  = (const float*)d_in[9];
    const float* b_fc1  = (const float*)d_in[10];
    const float* w_fc2  = (const float*)d_in[11];
    const float* b_fc2  = (const float*)d_in[12];
    float* out = (float*)d_out;

    // d_out reuse timeline:
    //   ln1 -> h (first 16.8MB) -> consumed by gemm_qkv
    //   attn partials: h0 [0,14.68MB), h1 [14.68,29.36MB), (m,l) 459KB at
    //   float offset 7340032 (29.36MB) -> consumed by attn_merge
    //   gemm_mlp overwrites all of d_out with the final fp32 output last.
    u16* h = (u16*)d_out;                      // LN1(x), then attn partials

    u16* W = (u16*)d_ws;
    u16* wqkvT  = W;                           // 768*256
    u16* wprojT = wqkvT + 196608;              // 256*256
    u16* wfc1T  = wprojT + 65536;              // 128*256
    u16* wfc2T  = wfc1T + 32768;               // 256*128
    u16* buf1   = wfc2T + 32768;               // q, then attn-out (in place)
    u16* buf2   = buf1 + (size_t)NROWS * 256;  // k, then x2
    u16* buf3   = buf2 + (size_t)NROWS * 256;  // vT (dead after attn)

    u16*   part  = h;                          // attn partials (bf16)
    float* mlbuf = (float*)d_out + 7340032;    // attn partial (m,l)

    transpose_weights<<<dim3(64), dim3(256), 0, stream>>>(
        w_qkv, wqkvT, w_proj, wprojT, w_fc1, wfc1T, w_fc2, wfc2T);
    ln_fused<float><<<dim3(NROWS / 4), dim3(256), 0, stream>>>(
        x, ln1_s, ln1_b, h);
    gemm_qkv<<<dim3(NROWS / 128, 6), dim3(256), 0, stream>>>(
        h, wqkvT, b_qkv, buf1, buf2, buf3);
    attn_kernel<<<dim3(480), dim3(512), 0, stream>>>(
        buf1, buf2, buf3, buf1, part, mlbuf);
    attn_merge<<<dim3(448), dim3(256), 0, stream>>>(
        part, mlbuf, buf1);
    gemm_proj<<<dim3(NROWS / 128, 2), dim3(256), 0, stream>>>(
        buf1, wprojT, b_proj, x, buf2);
    gemm_mlp<<<dim3(NROWS / 128), dim3(256), 0, stream>>>(
        buf2, ln2_s, ln2_b, wfc1T, b_fc1, wfc2T, b_fc2, out);
}

// Round 12
// 227.401 us; speedup vs baseline: 1.6379x; 1.0737x over previous
//
#include <hip/hip_runtime.h>
#include <hip/hip_bf16.h>

#define D_MODEL 256
#define D_HID   128
#define SEQ     1024
#define NBATCH  32
#define NROWS   (NBATCH * SEQ)    // 32768
#define MASKV   -10000.0f
#define EPSLN   1e-5f

typedef unsigned short u16;
using bf16x8 = __attribute__((ext_vector_type(8))) short;
using f32x4  = __attribute__((ext_vector_type(4))) float;

union U8 { uint4 v; u16 s[8]; };

__device__ __forceinline__ float bf2f(u16 u) {
    unsigned int x = ((unsigned int)u) << 16;
    return __uint_as_float(x);
}
__device__ __forceinline__ u16 f2bf(float f) {
    unsigned int u = __float_as_uint(f);
    u += 0x7fff + ((u >> 16) & 1);   // RNE
    return (u16)(u >> 16);
}
__device__ __forceinline__ void load4(const float* p, float* f) {
    float4 a = *(const float4*)p;
    f[0] = a.x; f[1] = a.y; f[2] = a.z; f[3] = a.w;
}
// async global->LDS, 16B per lane; LDS dest = wave-uniform base + lane*16
__device__ __forceinline__ void gload16(const u16* g, u16* l) {
    __builtin_amdgcn_global_load_lds(
        (const __attribute__((address_space(1))) void*)g,
        (__attribute__((address_space(3))) void*)l, 16, 0, 0);
}

// DPP cross-lane: VALU-pipe butterfly over 16-lane groups.
template <int CTRL>
__device__ __forceinline__ float dpp_mov(float v) {
    return __int_as_float(__builtin_amdgcn_update_dpp(
        0, __float_as_int(v), CTRL, 0xf, 0xf, true));
}
__device__ __forceinline__ float red16_max(float v) {
    v = fmaxf(v, dpp_mov<0xB1>(v));
    v = fmaxf(v, dpp_mov<0x4E>(v));
    v = fmaxf(v, dpp_mov<0x141>(v));
    v = fmaxf(v, dpp_mov<0x140>(v));
    return v;
}
__device__ __forceinline__ float red16_sum(float v) {
    v += dpp_mov<0xB1>(v);
    v += dpp_mov<0x4E>(v);
    v += dpp_mov<0x141>(v);
    v += dpp_mov<0x140>(v);
    return v;
}

// ---------------------------------------------------------------------------
// prep: fused weight transposes (blocks 0..63) + LN1 (blocks 64..8255).
// ---------------------------------------------------------------------------
__global__ __launch_bounds__(256) void prep_kernel(
    const float* __restrict__ wqkv, u16* __restrict__ wqkvT,
    const float* __restrict__ wproj, u16* __restrict__ wprojT,
    const float* __restrict__ wfc1, u16* __restrict__ wfc1T,
    const float* __restrict__ wfc2, u16* __restrict__ wfc2T,
    const float* __restrict__ x, const float* __restrict__ g1,
    const float* __restrict__ be1, u16* __restrict__ h) {
    if (blockIdx.x < 64) {
        int tid = blockIdx.x * 256 + threadIdx.x;
        const int stride = 64 * 256;
        for (int i = tid; i < 768 * 256; i += stride) {
            int n = i >> 8, k = i & 255;
            wqkvT[i] = f2bf(wqkv[k * 768 + n]);
        }
        for (int i = tid; i < 256 * 256; i += stride) {
            int n = i >> 8, k = i & 255;
            wprojT[i] = f2bf(wproj[k * 256 + n]);
        }
        for (int i = tid; i < 128 * 256; i += stride) {
            int n = i >> 8, k = i & 255;
            wfc1T[i] = f2bf(wfc1[k * 128 + n]);
        }
        for (int i = tid; i < 256 * 128; i += stride) {
            int n = i >> 7, k = i & 127;
            wfc2T[i] = f2bf(wfc2[k * 256 + n]);
        }
    } else {
        int wave = threadIdx.x >> 6, lane = threadIdx.x & 63;
        int row = (blockIdx.x - 64) * 4 + wave;
        float f[4];
        load4(x + (size_t)row * D_MODEL + lane * 4, f);
        float s  = f[0] + f[1] + f[2] + f[3];
        float sq = f[0] * f[0] + f[1] * f[1] + f[2] * f[2] + f[3] * f[3];
        #pragma unroll
        for (int off = 1; off < 64; off <<= 1) {
            s  += __shfl_xor(s, off);
            sq += __shfl_xor(sq, off);
        }
        float mu   = s * (1.0f / 256.0f);
        float var  = sq * (1.0f / 256.0f) - mu * mu;
        float rstd = rsqrtf(var + EPSLN);
        float g[4], be[4];
        load4(g1 + lane * 4, g);
        load4(be1 + lane * 4, be);
        ushort4 o;
        o.x = f2bf((f[0] - mu) * rstd * g[0] + be[0]);
        o.y = f2bf((f[1] - mu) * rstd * g[1] + be[1]);
        o.z = f2bf((f[2] - mu) * rstd * g[2] + be[2]);
        o.w = f2bf((f[3] - mu) * rstd * g[3] + be[3]);
        *(ushort4*)(h + (size_t)row * D_MODEL + lane * 4) = o;
    }
}

// ---------------------------------------------------------------------------
// 128x128 GEMM tile mainloop (m97-class): single 64-KB LDS buffer, staged via
// global_load_lds width-16 with inverse-XOR-swizzled GLOBAL source (rule #21);
// ds_read_b128 frag reads apply the same XOR -> 2-way (free) bank aliasing.
// 4 waves in 2x2, each owns a 64x64 quadrant (acc[4][4]).
// ---------------------------------------------------------------------------
#define GT2_ELEMS (2 * 128 * 128)   // A tile + B tile, 64 KB

template <int K>
__device__ __forceinline__ void gemm_tile2(
    const u16* __restrict__ A, const u16* __restrict__ BT,
    int m0, int n0, u16* lds, f32x4 acc[4][4]) {
    u16* ldsA = lds;
    u16* ldsB = lds + 128 * 128;
    const int tid = threadIdx.x;
    const int lane = tid & 63, wave = tid >> 6;
    const int wr = (wave >> 1) * 64, wc = (wave & 1) * 64;
    const int row = lane & 15, quad = lane >> 4;

    for (int ks = 0; ks < K; ks += 128) {
        __syncthreads();
        #pragma unroll
        for (int i = 0; i < 8; i++) {
            int blk = i * 4 + wave;               // 1-KB block 0..31
            int B = (blk << 10) + lane * 16;      // byte offset in 32-KB tile
            int r = B >> 8;                       // tile row (256-B rows)
            int cb = (B & 255) ^ ((r & 7) << 4);  // inverse-swizzled byte col
            gload16(A + (size_t)(m0 + r) * K + ks + (cb >> 1),
                    ldsA + (blk << 9));
            gload16(BT + (size_t)(n0 + r) * K + ks + (cb >> 1),
                    ldsB + (blk << 9));
        }
        __syncthreads();
        #pragma unroll
        for (int k0 = 0; k0 < 128; k0 += 32) {
            bf16x8 a[4], b[4];
            #pragma unroll
            for (int mi = 0; mi < 4; mi++) {
                int rr = wr + mi * 16 + row;
                a[mi] = *(const bf16x8*)(ldsA + rr * 128 +
                         ((k0 + quad * 8) ^ ((rr & 7) << 3)));
            }
            #pragma unroll
            for (int nj = 0; nj < 4; nj++) {
                int rr = wc + nj * 16 + row;
                b[nj] = *(const bf16x8*)(ldsB + rr * 128 +
                         ((k0 + quad * 8) ^ ((rr & 7) << 3)));
            }
            #pragma unroll
            for (int mi = 0; mi < 4; mi++)
                #pragma unroll
                for (int nj = 0; nj < 4; nj++)
                    acc[mi][nj] = __builtin_amdgcn_mfma_f32_16x16x32_bf16(
                        a[mi], b[nj], acc[mi][nj], 0, 0, 0);
        }
    }
}

#define ZERO_ACC4(acc)                                       \
    _Pragma("unroll") for (int i_ = 0; i_ < 4; i_++)         \
    _Pragma("unroll") for (int j_ = 0; j_ < 4; j_++)         \
    _Pragma("unroll") for (int e_ = 0; e_ < 4; e_++) acc[i_][j_][e_] = 0.0f;

#define EPILOG_IDX4                                          \
    int lane = threadIdx.x & 63, wave = threadIdx.x >> 6;    \
    int wr = (wave >> 1) * 64, wc = (wave & 1) * 64;         \
    int row = lane & 15, quad = lane >> 4;

// QKV: h @ wqkv + b -> q (pre-scaled 1/16), k, vT[b,256,s]
__global__ __launch_bounds__(256) void gemm_qkv(
    const u16* __restrict__ h, const u16* __restrict__ wqkvT,
    const float* __restrict__ b_qkv,
    u16* __restrict__ q, u16* __restrict__ kk, u16* __restrict__ vT) {
    __shared__ u16 lds[GT2_ELEMS];
    f32x4 acc[4][4];
    ZERO_ACC4(acc)
    int m0 = blockIdx.x * 128, n0 = blockIdx.y * 128;
    gemm_tile2<256>(h, wqkvT, m0, n0, lds, acc);
    EPILOG_IDX4
    #pragma unroll
    for (int mi = 0; mi < 4; mi++) {
        #pragma unroll
        for (int nj = 0; nj < 4; nj++) {
            int gn = n0 + wc + nj * 16 + row;
            float bias = b_qkv[gn];
            int gm = m0 + wr + mi * 16 + quad * 4;
            if (gn < 256) {          // q, pre-scaled by 1/sqrt(D)=1/16
                #pragma unroll
                for (int r = 0; r < 4; r++)
                    q[(size_t)(gm + r) * 256 + gn] =
                        f2bf((acc[mi][nj][r] + bias) * 0.0625f);
            } else if (gn < 512) {   // k
                int col = gn - 256;
                #pragma unroll
                for (int r = 0; r < 4; r++)
                    kk[(size_t)(gm + r) * 256 + col] = f2bf(acc[mi][nj][r] + bias);
            } else {                 // v -> vT[b][d][s]
                int d = gn - 512;
                int b = gm >> 10, s = gm & 1023;
                ushort4 pack;
                pack.x = f2bf(acc[mi][nj][0] + bias);
                pack.y = f2bf(acc[mi][nj][1] + bias);
                pack.z = f2bf(acc[mi][nj][2] + bias);
                pack.w = f2bf(acc[mi][nj][3] + bias);
                *(ushort4*)(vT + ((size_t)(b * 256 + d) << 10) + s) = pack;
            }
        }
    }
}

// ---------------------------------------------------------------------------
// gemm_proj_m: attn-merge FUSED into proj. Each A-tile (128 rows) is exactly
// one (b,qt) row-block. qt==0: rows are final in ao -> gload16 direct.
// qt>=1: merge h0/h1 unnormalized partials in registers (per-row scales
// precomputed into LDS) and ds_write the swizzled A-tile. Kills the separate
// attn_merge kernel + its 28.6MB HBM round-trip; merge hides under B-staging.
// ---------------------------------------------------------------------------
__global__ __launch_bounds__(256) void gemm_proj_m(
    const u16* __restrict__ part, const float* __restrict__ ml,
    const u16* __restrict__ aoq0, const u16* __restrict__ wprojT,
    const float* __restrict__ b_proj, const float* __restrict__ x_in,
    u16* __restrict__ x2) {
    __shared__ u16 lds[GT2_ELEMS];
    __shared__ float s_sc[2][128];
    u16* ldsA = lds;
    u16* ldsB = lds + 128 * 128;
    const int tid = threadIdx.x;
    const int lane = tid & 63, wave = tid >> 6;
    const int wr = (wave >> 1) * 64, wc = (wave & 1) * 64;
    const int row = lane & 15, quad = lane >> 4;
    int m0 = blockIdx.x * 128, n0 = blockIdx.y * 128;
    int b = m0 >> 10, qt = (m0 >> 7) & 7;
    int pq = b * 7 + qt - 1;

    if (qt && tid < 128) {               // per-row merge scales
        const float* pA = ml + ((size_t)((pq * 2 + 0) * 128 + tid)) * 2;
        const float* pB = ml + ((size_t)((pq * 2 + 1) * 128 + tid)) * 2;
        float mA = pA[0], lA = pA[1];
        float mB = pB[0], lB = pB[1];
        float m  = fmaxf(mA, mB);
        float eA = __expf(mA - m), eB = __expf(mB - m);
        float inv = 1.0f / (lA * eA + lB * eB);
        s_sc[0][tid] = eA * inv;
        s_sc[1][tid] = eB * inv;
    }

    f32x4 acc[4][4];
    ZERO_ACC4(acc)
    for (int ks = 0; ks < 256; ks += 128) {
        __syncthreads();                 // also covers s_sc on first iter
        if (qt == 0) {
            #pragma unroll
            for (int i = 0; i < 8; i++) {
                int blk = i * 4 + wave;
                int B = (blk << 10) + lane * 16;
                int r = B >> 8;
                int cb = (B & 255) ^ ((r & 7) << 4);
                gload16(aoq0 + (size_t)(m0 + r) * 256 + ks + (cb >> 1),
                        ldsA + (blk << 9));
                gload16(wprojT + (size_t)(n0 + r) * 256 + ks + (cb >> 1),
                        ldsB + (blk << 9));
            }
        } else {
            #pragma unroll
            for (int i = 0; i < 8; i++) {
                int blk = i * 4 + wave;
                int B = (blk << 10) + lane * 16;
                int r = B >> 8;
                int cb = (B & 255) ^ ((r & 7) << 4);
                gload16(wprojT + (size_t)(n0 + r) * 256 + ks + (cb >> 1),
                        ldsB + (blk << 9));
            }
            const u16* p0 = part + ((size_t)pq << 15);
            const u16* p1 = part + ((size_t)(224 + pq) << 15);
            #pragma unroll
            for (int i = 0; i < 8; i++) {
                int cchunk = i * 256 + tid;          // 16B chunk 0..2047
                int Bb = cchunk * 16;
                int r = Bb >> 8, cb_lin = Bb & 255;
                U8 a, bb, o;
                a.v  = *(const uint4*)(p0 + (size_t)r * 256 + ks + (cb_lin >> 1));
                bb.v = *(const uint4*)(p1 + (size_t)r * 256 + ks + (cb_lin >> 1));
                float sA = s_sc[0][r], sB = s_sc[1][r];
                #pragma unroll
                for (int e = 0; e < 8; e++)
                    o.s[e] = f2bf(bf2f(a.s[e]) * sA + bf2f(bb.s[e]) * sB);
                *(uint4*)((char*)ldsA + r * 256 + (cb_lin ^ ((r & 7) << 4))) = o.v;
            }
        }
        __syncthreads();
        #pragma unroll
        for (int k0 = 0; k0 < 128; k0 += 32) {
            bf16x8 a[4], bfr[4];
            #pragma unroll
            for (int mi = 0; mi < 4; mi++) {
                int rr = wr + mi * 16 + row;
                a[mi] = *(const bf16x8*)(ldsA + rr * 128 +
                         ((k0 + quad * 8) ^ ((rr & 7) << 3)));
            }
            #pragma unroll
            for (int nj = 0; nj < 4; nj++) {
                int rr = wc + nj * 16 + row;
                bfr[nj] = *(const bf16x8*)(ldsB + rr * 128 +
                         ((k0 + quad * 8) ^ ((rr & 7) << 3)));
            }
            #pragma unroll
            for (int mi = 0; mi < 4; mi++)
                #pragma unroll
                for (int nj = 0; nj < 4; nj++)
                    acc[mi][nj] = __builtin_amdgcn_mfma_f32_16x16x32_bf16(
                        a[mi], bfr[nj], acc[mi][nj], 0, 0, 0);
        }
    }
    #pragma unroll
    for (int mi = 0; mi < 4; mi++)
        #pragma unroll
        for (int nj = 0; nj < 4; nj++) {
            int gn = n0 + wc + nj * 16 + row;
            float bias = b_proj[gn];
            int gm = m0 + wr + mi * 16 + quad * 4;
            #pragma unroll
            for (int r = 0; r < 4; r++) {
                size_t idx = (size_t)(gm + r) * 256 + gn;
                x2[idx] = f2bf(acc[mi][nj][r] + bias + x_in[idx]);
            }
        }
}

// ---------------------------------------------------------------------------
// gemm_mlp: fused LN2 + fc1(ReLU) + fc2 + residual. One block per 128 rows,
// now 512 threads (8 waves) for latency hiding at 1 block/CU; 128 KB LDS.
//   R0 (64KB): x2 tile (LN'd in place) -> later reused for wfc2T
//   R1 (32KB): wfc1T k-half staging
//   R2 (32KB): a1 = relu(fc1) bf16 128x128
// fc1 wave tile 32x64 (acc[2][4]); fc2 wave tile 32x128 (acc[2][8]).
// ---------------------------------------------------------------------------
__global__ __launch_bounds__(512) void gemm_mlp(
    const u16* __restrict__ x2, const float* __restrict__ g2,
    const float* __restrict__ be2,
    const u16* __restrict__ wfc1T, const float* __restrict__ b_fc1,
    const u16* __restrict__ wfc2T, const float* __restrict__ b_fc2,
    float* __restrict__ out) {
    __shared__ u16 lds[65536];            // 128 KB
    u16* ldsB1 = lds + 32768;             // R1
    u16* ldsA1 = lds + 49152;             // R2
    const int tid = threadIdx.x;
    const int lane = tid & 63, wave = tid >> 6;   // wave 0..7
    const int rowl = lane & 15, quad = lane >> 4;
    const int wr = (wave >> 1) * 32, wc = (wave & 1) * 64;
    const int m0 = blockIdx.x * 128;

    // ---- stage x2 tile (128 x 512B = 64 KB) + wfc1T ks=0 half (32 KB) ----
    #pragma unroll
    for (int i = 0; i < 8; i++) {
        int blk = i * 8 + wave;
        int B = (blk << 10) + lane * 16;
        int r = B >> 9;
        int cb = (B & 511) ^ ((r & 7) << 4);
        gload16(x2 + (size_t)(m0 + r) * 256 + (cb >> 1), lds + (B >> 1));
    }
    #pragma unroll
    for (int i = 0; i < 4; i++) {
        int blk = i * 8 + wave;
        int B = (blk << 10) + lane * 16;
        int r = B >> 8;
        int cb = (B & 255) ^ ((r & 7) << 4);
        gload16(wfc1T + (size_t)r * 256 + 0 + (cb >> 1), ldsB1 + (B >> 1));
    }
    __syncthreads();

    // ---- LN2 in place: wave handles rows wave, wave+8, ... (16 rows) ----
    {
        float4 g4  = *(const float4*)(g2 + lane * 4);
        float4 be4 = *(const float4*)(be2 + lane * 4);
        #pragma unroll 4
        for (int i = 0; i < 16; i++) {
            int r = wave + i * 8;
            char* p = (char*)lds + r * 512 + ((lane * 8) ^ ((r & 7) << 4));
            ushort4 v = *(ushort4*)p;
            float f0 = bf2f(v.x), f1 = bf2f(v.y), f2v = bf2f(v.z), f3 = bf2f(v.w);
            float s  = f0 + f1 + f2v + f3;
            float sq = f0*f0 + f1*f1 + f2v*f2v + f3*f3;
            s = red16_sum(s);   s += __shfl_xor(s, 16);   s += __shfl_xor(s, 32);
            sq = red16_sum(sq); sq += __shfl_xor(sq, 16); sq += __shfl_xor(sq, 32);
            float mu   = s * (1.0f / 256.0f);
            float var  = sq * (1.0f / 256.0f) - mu * mu;
            float rstd = rsqrtf(var + EPSLN);
            ushort4 o;
            o.x = f2bf((f0  - mu) * rstd * g4.x + be4.x);
            o.y = f2bf((f1  - mu) * rstd * g4.y + be4.y);
            o.z = f2bf((f2v - mu) * rstd * g4.z + be4.z);
            o.w = f2bf((f3  - mu) * rstd * g4.w + be4.w);
            *(ushort4*)p = o;
        }
    }
    __syncthreads();

    // ---- fc1: h2tile(128x256) @ wfc1 -> acc1 (wave tile 32x64) ----
    f32x4 acc1[2][4];
    #pragma unroll
    for (int mi = 0; mi < 2; mi++)
        #pragma unroll
        for (int nj = 0; nj < 4; nj++)
            #pragma unroll
            for (int e = 0; e < 4; e++) acc1[mi][nj][e] = 0.0f;
    #pragma unroll
    for (int ks = 0; ks < 256; ks += 128) {
        if (ks) {
            __syncthreads();          // done reading previous B1 half
            #pragma unroll
            for (int i = 0; i < 4; i++) {
                int blk = i * 8 + wave;
                int B = (blk << 10) + lane * 16;
                int r = B >> 8;
                int cb = (B & 255) ^ ((r & 7) << 4);
                gload16(wfc1T + (size_t)r * 256 + ks + (cb >> 1),
                        ldsB1 + (B >> 1));
            }
            __syncthreads();
        }
        #pragma unroll
        for (int k0 = 0; k0 < 128; k0 += 32) {
            bf16x8 a[2], b[4];
            #pragma unroll
            for (int mi = 0; mi < 2; mi++) {
                int rr = wr + mi * 16 + rowl;
                a[mi] = *(const bf16x8*)((const char*)lds + rr * 512 +
                         ((((ks + k0 + quad * 8) << 1)) ^ ((rr & 7) << 4)));
            }
            #pragma unroll
            for (int nj = 0; nj < 4; nj++) {
                int rb = wc + nj * 16 + rowl;
                b[nj] = *(const bf16x8*)((const char*)ldsB1 + rb * 256 +
                         ((((k0 + quad * 8) << 1)) ^ ((rb & 7) << 4)));
            }
            #pragma unroll
            for (int mi = 0; mi < 2; mi++)
                #pragma unroll
                for (int nj = 0; nj < 4; nj++)
                    acc1[mi][nj] = __builtin_amdgcn_mfma_f32_16x16x32_bf16(
                        a[mi], b[nj], acc1[mi][nj], 0, 0, 0);
        }
    }
    // relu+bias -> a1 (LDS, swizzled scalar writes)
    #pragma unroll
    for (int mi = 0; mi < 2; mi++)
        #pragma unroll
        for (int nj = 0; nj < 4; nj++) {
            int gn_l = wc + nj * 16 + rowl;
            float bias = b_fc1[gn_l];
            #pragma unroll
            for (int r = 0; r < 4; r++) {
                int gm_l = wr + mi * 16 + quad * 4 + r;
                *(u16*)((char*)ldsA1 + gm_l * 256 +
                        (((gn_l << 1)) ^ ((gm_l & 7) << 4))) =
                    f2bf(fmaxf(acc1[mi][nj][r] + bias, 0.0f));
            }
        }
    __syncthreads();                  // a1 visible; x2 tile (R0) now dead

    // ---- stage wfc2T (256 rows x 256B = 64 KB) into R0 ----
    #pragma unroll
    for (int i = 0; i < 8; i++) {
        int blk = i * 8 + wave;
        int B = (blk << 10) + lane * 16;
        int r = B >> 8;
        int cb = (B & 255) ^ ((r & 7) << 4);
        gload16(wfc2T + (size_t)r * 128 + (cb >> 1), lds + (B >> 1));
    }
    __syncthreads();

    // ---- fc2: a1(128x128) @ wfc2 -> out (wave tile 32x128) ----
    const int wc2 = (wave & 1) * 128;
    f32x4 acc2[2][8];
    #pragma unroll
    for (int mi = 0; mi < 2; mi++)
        #pragma unroll
        for (int nj = 0; nj < 8; nj++)
            #pragma unroll
            for (int e = 0; e < 4; e++) acc2[mi][nj][e] = 0.0f;
    #pragma unroll
    for (int k0 = 0; k0 < 128; k0 += 32) {
        bf16x8 a[2], b[8];
        #pragma unroll
        for (int mi = 0; mi < 2; mi++) {
            int rr = wr + mi * 16 + rowl;
            a[mi] = *(const bf16x8*)((const char*)ldsA1 + rr * 256 +
                     ((((k0 + quad * 8) << 1)) ^ ((rr & 7) << 4)));
        }
        #pragma unroll
        for (int nj = 0; nj < 8; nj++) {
            int rb = wc2 + nj * 16 + rowl;
            b[nj] = *(const bf16x8*)((const char*)lds + rb * 256 +
                     ((((k0 + quad * 8) << 1)) ^ ((rb & 7) << 4)));
        }
        #pragma unroll
        for (int mi = 0; mi < 2; mi++)
            #pragma unroll
            for (int nj = 0; nj < 8; nj++)
                acc2[mi][nj] = __builtin_amdgcn_mfma_f32_16x16x32_bf16(
                    a[mi], b[nj], acc2[mi][nj], 0, 0, 0);
    }
    #pragma unroll
    for (int mi = 0; mi < 2; mi++)
        #pragma unroll
        for (int nj = 0; nj < 8; nj++) {
            int gn = wc2 + nj * 16 + rowl;
            float bias = b_fc2[gn];
            int gm = m0 + wr + mi * 16 + quad * 4;
            #pragma unroll
            for (int r = 0; r < 4; r++) {
                size_t idx = (size_t)(gm + r) * 256 + gn;
                out[idx] = acc2[mi][nj][r] + bias + bf2f(x2[idx]);
            }
        }
}

// ---------------------------------------------------------------------------
// Flash attention v12 (round-11 winner, UNCHANGED): 512-thread blocks
// (8 waves x 16 rows = 128 q-rows); plain __launch_bounds__(512) (the (512,4)
// form forced VGPR 64 -> spill catastrophe). Both split halves write
// unnormalized partials; qt=0 whole (sole Q reader) writes ao directly.
// 15 chunks/batch, grid 480; co-resident pairs (c,c+8) sum 18-20.
// Measured 59.7 us. Partials merged inside gemm_proj_m now.
// ---------------------------------------------------------------------------
__constant__ unsigned char CQT[15] = {7,6,6,5,5,4,4,7, 0,1,1,2,2,3,3};
__constant__ unsigned char CH[15]  = {0,0,1,0,1,0,1,1, 2,0,1,0,1,0,1};

__global__ __launch_bounds__(512) void attn_kernel(
    const u16* __restrict__ q, const u16* __restrict__ k,
    const u16* __restrict__ vT, u16* __restrict__ ao,
    u16* __restrict__ part, float* __restrict__ ml) {
    __shared__ u16 k_lds[2][32 * 256];   // 2 x 16 KB, K tile [s][d]
    __shared__ u16 v_lds[2][256 * 32];   // 2 x 16 KB, V^T tile [d][s]
    __shared__ u16 p_lds[8][16 * 40];    // 10 KB, wave-private P staging

    int j = blockIdx.x;
    int b = j & 31, c = j >> 5;          // batch fast-varying: XCD = b % 8
    int qt = CQT[c], ch = CH[c];
    int span = 2 * qt + 2;
    int lo, hi;
    if (ch == 2) { lo = 0; hi = 4; }            // qt=0 whole (4 tiles)
    else         { lo = ch * span; hi = lo + span; }

    int tid = threadIdx.x;
    int lane = tid & 63, wave = tid >> 6;   // wave 0..7
    int row = lane & 15, quad = lane >> 4;
    int qrow0 = qt * 128 + wave * 16;

    const u16* qb = q + ((size_t)b << 10) * 256;
    const u16* kb = k + ((size_t)b << 10) * 256;
    const u16* vb = vT + (((size_t)b * 256) << 10);

    const int kxor = (row & 7) << 3;   // u16-unit XOR for K reads
    const int vxor = (row & 6) << 2;   // u16-unit XOR for V reads

    // Q fragments held in registers for the whole kernel (pre-scaled by 1/16)
    bf16x8 qf[8];
    #pragma unroll
    for (int kf = 0; kf < 8; kf++)
        qf[kf] = *(const bf16x8*)(qb + (size_t)(qrow0 + row) * 256 + kf * 32 + quad * 8);

    f32x4 o[16];
    #pragma unroll
    for (int n = 0; n < 16; n++)
        #pragma unroll
        for (int e = 0; e < 4; e++) o[n][e] = 0.0f;
    float m_i[4], l_i[4];
    #pragma unroll
    for (int r = 0; r < 4; r++) { m_i[r] = -1e30f; l_i[r] = 0.0f; }

    int wlast = 4 * qt + (wave >> 1);    // this wave's diagonal k-tile

    // stage tile kt: 8 waves x (2 K-blocks + 2 V-blocks) x 1 KB
    auto stage = [&](int bf, int kt) {
        int k0 = kt << 5;
        #pragma unroll
        for (int cc = 0; cc < 2; cc++) {
            int blk = wave * 2 + cc;                  // 0..15
            int B = (blk << 10) + lane * 16;          // byte offset in 16KB tile
            // K: 32 rows x 512 B
            int rk = B >> 9;
            int ck = (B & 511) ^ ((rk & 7) << 4);
            gload16(kb + (size_t)(k0 + rk) * 256 + (ck >> 1),
                    &k_lds[bf][blk << 9]);
            // V^T: 256 rows x 64 B
            int rv = B >> 6;
            int cv = (B & 63) ^ ((rv & 6) << 3);
            gload16(vb + ((size_t)rv << 10) + k0 + (cv >> 1),
                    &v_lds[bf][blk << 9]);
        }
    };

    stage(0, lo);
    __syncthreads();                       // vmcnt(0) drain + barrier

    for (int kt = lo; kt < hi; kt++) {
        int cur = (kt - lo) & 1;
        if (kt + 1 < hi) stage(cur ^ 1, kt + 1);   // prefetch next tile
        if (kt <= wlast) {
            const u16* kl = k_lds[cur];
            const u16* vl = v_lds[cur];

            // S = Q K^T : 16 x 32
            f32x4 sf[2];
            #pragma unroll
            for (int jn = 0; jn < 2; jn++)
                #pragma unroll
                for (int e = 0; e < 4; e++) sf[jn][e] = 0.0f;
            __builtin_amdgcn_s_setprio(1);
            #pragma unroll
            for (int kf = 0; kf < 8; kf++)
                #pragma unroll
                for (int jn = 0; jn < 2; jn++) {
                    bf16x8 bfrag = *(const bf16x8*)(kl +
                        ((((jn * 16 + row) * 256) + kf * 32 + quad * 8) ^ kxor));
                    sf[jn] = __builtin_amdgcn_mfma_f32_16x16x32_bf16(
                        qf[kf], bfrag, sf[jn], 0, 0, 0);
                }
            __builtin_amdgcn_s_setprio(0);

            int kk0 = kt * 32;
            bool diag = (kt == wlast);     // only the diagonal tile masks
            int qrow = qrow0 + quad * 4;
            float sv[2][4];
            #pragma unroll
            for (int jn = 0; jn < 2; jn++)
                #pragma unroll
                for (int r = 0; r < 4; r++) {
                    float v = sf[jn][r];
                    if (diag && (kk0 + jn * 16 + row > qrow + r)) v = MASKV;
                    sv[jn][r] = v;
                }

            // online softmax with defer-max (THR=8); DPP reduces (VALU pipe)
            float pmax[4];
            int need = 0;
            #pragma unroll
            for (int r = 0; r < 4; r++) {
                pmax[r] = red16_max(fmaxf(sv[0][r], sv[1][r]));
                need |= (pmax[r] > m_i[r] + 8.0f) ? 1 : 0;
            }
            if (__any(need)) {
                #pragma unroll
                for (int r = 0; r < 4; r++) {
                    float mnew = fmaxf(m_i[r], pmax[r]);
                    float al = __expf(m_i[r] - mnew);
                    m_i[r] = mnew;
                    l_i[r] *= al;
                    #pragma unroll
                    for (int n = 0; n < 16; n++) o[n][r] *= al;
                }
            }
            #pragma unroll
            for (int r = 0; r < 4; r++) {
                float ps = 0.0f;
                #pragma unroll
                for (int jn = 0; jn < 2; jn++) {
                    sv[jn][r] = __expf(sv[jn][r] - m_i[r]);
                    ps += sv[jn][r];
                }
                l_i[r] += red16_sum(ps);
            }

            // P: C-layout -> wave-private LDS -> A-layout (one frag, K=32)
            u16* pw = p_lds[wave];
            #pragma unroll
            for (int jn = 0; jn < 2; jn++)
                #pragma unroll
                for (int r = 0; r < 4; r++)
                    pw[(quad * 4 + r) * 40 + jn * 16 + row] = f2bf(sv[jn][r]);
            bf16x8 pf = *(const bf16x8*)(pw + row * 40 + quad * 8);

            // O += P V
            __builtin_amdgcn_s_setprio(1);
            #pragma unroll
            for (int n = 0; n < 16; n++) {
                bf16x8 bv = *(const bf16x8*)(vl +
                    ((((n * 16 + row) * 32) + quad * 8) ^ vxor));
                o[n] = __builtin_amdgcn_mfma_f32_16x16x32_bf16(pf, bv, o[n], 0, 0, 0);
            }
            __builtin_amdgcn_s_setprio(0);
        }
        __syncthreads();   // vmcnt(0): prefetched tile landed; buffers swap
    }

    if (ch == 2) {
        // qt=0 whole: sole reader of its Q rows -> safe to write ao directly
        float inv[4];
        #pragma unroll
        for (int r = 0; r < 4; r++) inv[r] = 1.0f / l_i[r];
        u16* aob = ao + (((size_t)b << 10) + qrow0) * 256;
        #pragma unroll
        for (int r = 0; r < 4; r++)
            #pragma unroll
            for (int n = 0; n < 16; n++)
                aob[(size_t)(quad * 4 + r) * 256 + n * 16 + row] =
                    f2bf(o[n][r] * inv[r]);
    } else {
        // split half: write UNNORMALIZED O partial + (m,l); proj_m merges.
        int pq = b * 7 + (qt - 1);           // 0..223
        u16* pb = part + ((size_t)(ch * 224 + pq) << 15);
        #pragma unroll
        for (int r = 0; r < 4; r++) {
            int rt = wave * 16 + quad * 4 + r;
            #pragma unroll
            for (int n = 0; n < 16; n++)
                pb[(size_t)rt * 256 + n * 16 + row] = f2bf(o[n][r]);
        }
        if (row == 0) {
            int p = pq * 2 + ch;
            #pragma unroll
            for (int r = 0; r < 4; r++) {
                int rt = wave * 16 + quad * 4 + r;
                float2 v2; v2.x = m_i[r]; v2.y = l_i[r];
                *(float2*)(ml + ((size_t)(p * 128 + rt)) * 2) = v2;
            }
        }
    }
}

// ---------------------------------------------------------------------------
extern "C" void kernel_launch(void* const* d_in, const int* in_sizes, int n_in,
                              void* d_out, int out_size, void* d_ws, size_t ws_size,
                              hipStream_t stream) {
    const float* x      = (const float*)d_in[0];
    const float* ln1_s  = (const float*)d_in[1];
    const float* ln1_b  = (const float*)d_in[2];
    const float* w_qkv  = (const float*)d_in[3];
    const float* b_qkv  = (const float*)d_in[4];
    const float* w_proj = (const float*)d_in[5];
    const float* b_proj = (const float*)d_in[6];
    const float* ln2_s  = (const float*)d_in[7];
    const float* ln2_b  = (const float*)d_in[8];
    const float* w_fc1  = (const float*)d_in[9];
    const float* b_fc1  = (const float*)d_in[10];
    const float* w_fc2  = (const float*)d_in[11];
    const float* b_fc2  = (const float*)d_in[12];
    float* out = (float*)d_out;

    // d_out reuse timeline:
    //   prep -> h (first 16.8MB) -> consumed by gemm_qkv
    //   attn partials: h0 [0,14.68MB), h1 [14.68,29.36MB), (m,l) 459KB at
    //   float offset 7340032 (29.36MB) -> consumed by gemm_proj_m
    //   gemm_mlp overwrites all of d_out with the final fp32 output last.
    u16* h = (u16*)d_out;                      // LN1(x), then attn partials

    u16* W = (u16*)d_ws;
    u16* wqkvT  = W;                           // 768*256
    u16* wprojT = wqkvT + 196608;              // 256*256
    u16* wfc1T  = wprojT + 65536;              // 128*256
    u16* wfc2T  = wfc1T + 32768;               // 256*128
    u16* buf1   = wfc2T + 32768;               // q, then attn qt0-out (in place)
    u16* buf2   = buf1 + (size_t)NROWS * 256;  // k, then x2
    u16* buf3   = buf2 + (size_t)NROWS * 256;  // vT (dead after attn)

    u16*   part  = h;                          // attn partials (bf16)
    float* mlbuf = (float*)d_out + 7340032;    // attn partial (m,l)

    prep_kernel<<<dim3(64 + NROWS / 4), dim3(256), 0, stream>>>(
        w_qkv, wqkvT, w_proj, wprojT, w_fc1, wfc1T, w_fc2, wfc2T,
        x, ln1_s, ln1_b, h);
    gemm_qkv<<<dim3(NROWS / 128, 6), dim3(256), 0, stream>>>(
        h, wqkvT, b_qkv, buf1, buf2, buf3);
    attn_kernel<<<dim3(480), dim3(512), 0, stream>>>(
        buf1, buf2, buf3, buf1, part, mlbuf);
    gemm_proj_m<<<dim3(NROWS / 128, 2), dim3(256), 0, stream>>>(
        part, mlbuf, buf1, wprojT, b_proj, x, buf2);
    gemm_mlp<<<dim3(NROWS / 128), dim3(512), 0, stream>>>(
        buf2, ln2_s, ln2_b, wfc1T, b_fc1, wfc2T, b_fc2, out);
}